// Round 6
// baseline (283.111 us; speedup 1.0000x reference)
//
#include <hip/hip_runtime.h>
#include <hip/hip_bf16.h>

#define TT 336
#define NF 321
#define NB 64
#define NSER (NB * NF)   // 20544 series
#define WPB 4            // waves (series) per block in FALLBACK series kernel
#define KP 352           // Wb row stride (zero-padded tail k in [336,352))
#define LDA2 340         // sA row stride (ushorts): 680B = 170 words == 10 mod 32
                         // -> 16-lane write pattern hits 16 distinct banks
#define SPP 16           // series per fused block (64B line = 16 floats)
#define WV 8             // waves per fused block (512 threads)
#define NFB (NSER / SPP)     // 1284 fused blocks
#define NFBG 1288            // dispatched (8 x 161, guard skips 4)
#define TSP 338          // ts row stride float2: 2704B == 16 mod 128 -> 2-way free

// per-wave boundary tables overlay the wave's own 2 consumed ts rows:
// [3 periods][70 slots][5 stats] + totals[5] = 4224B <= 2*2704B
#define TWS 1056

// transpose grid (fallback paths): 11 x 11 x 64 blocks
#define TGX 11
#define TGY 11
#define NMSEP (TGX * TGY * NB)   // 7744 per-block MSE partials (fallback)

typedef __attribute__((ext_vector_type(8))) short bf16x8;
typedef __attribute__((ext_vector_type(4))) float f32x4;
typedef unsigned long long ULL;

__device__ __forceinline__ unsigned short f2bf(float v) {
    unsigned x = __float_as_uint(v);
    x += 0x7FFFu + ((x >> 16) & 1u);   // RNE; inputs are finite
    return (unsigned short)(x >> 16);
}

// sorted-3 insert (a0 >= a1 >= a2)
__device__ __forceinline__ void ins3(ULL& a0, ULL& a1, ULL& a2, ULL x) {
    ULL hi = a0 > x ? a0 : x;
    ULL lo = a0 > x ? x : a0;
    a0 = hi;
    ULL hi1 = a1 > lo ? a1 : lo;
    ULL lo1 = a1 > lo ? lo : a1;
    a1 = hi1;
    a2 = a2 > lo1 ? a2 : lo1;
}

// exact integer 336/d via fast fp32 division (error ~1e-7 rel, 100x margin
// to the 1/336 distance from integer boundaries). d>336 (garbage) -> 0.
__device__ __forceinline__ int idiv336(int d) {
    return (int)(__fdividef(336.0f, (float)d));
}

// ---------------------------------------------------------------------------
// Twiddle matrix: Wb[n][k], n=2(f-1) -> cos(2pi f k/336), n=2(f-1)+1 -> sin.
// Tail k in [336,352) is ZERO — the fused kernel's masked tail MFMA relies
// on it.
// ---------------------------------------------------------------------------
__global__ void twiddle_k(unsigned short* __restrict__ Wb) {
    int n = blockIdx.x;          // 0..335
    int f = (n >> 1) + 1;
    int isSin = n & 1;
    for (int k = threadIdx.x; k < KP; k += blockDim.x) {
        float v = 0.0f;
        if (k < TT) {
            int r = (f * k) % TT;
            float ang = 6.2831853071795864769f * (float)r / 336.0f;
            v = isSin ? sinf(ang) : cosf(ang);
        }
        Wb[(size_t)n * KP + k] = f2bf(v);
    }
}

// ---------------------------------------------------------------------------
// All-fp32 patch loss (r16: matches the fp32 JAX reference; absmax 0.0625,
// deterministic, inside tolerance).
// ---------------------------------------------------------------------------
__device__ __forceinline__ float patch_loss_f32(float S1, float S2, float S3,
                                                float S4, float S5, int n) {
    float nnf = (float)n;
    float invf = 1.0f / nnf;
    float tvs = S3 - S1 * S1 * invf; tvs = tvs > 0.f ? tvs : 0.f;
    float fvs = S4 - S2 * S2 * invf; fvs = fvs > 0.f ? fvs : 0.f;
    float num = S5 - S1 * S2 * invf;
    float corr = num / (sqrtf(tvs * fvs) + 1e-8f);
    float closs = 1.0f - fabsf(corr);
    float vloss = fabsf(tvs - fvs) / (tvs + (nnf - 1.0f) * 1e-8f);
    float mloss = fabsf(S1 - S2) / (fabsf(S1) + nnf * 1e-8f);
    return closs + vloss + mloss;
}

// full-fp64 patch loss (fallback series kernel only)
__device__ __forceinline__ double patch_loss(double S1, double S2, double S3,
                                             double S4, double S5, double nn) {
    double mt = S1 / nn, mf = S2 / nn;
    double tvs = S3 - nn * mt * mt; tvs = tvs > 0.0 ? tvs : 0.0;
    double fvs = S4 - nn * mf * mf; fvs = fvs > 0.0 ? fvs : 0.0;
    double num = S5 - nn * mt * mf;
    double corr = num / (sqrt(tvs * fvs) + 1e-8);
    double closs = 1.0 - fabs(corr);
    double tvar = tvs / (nn - 1.0), fvar = fvs / (nn - 1.0);
    double vloss = fabs(tvar - fvar) / (tvar + 1e-8);
    double mloss = fabs(mt - mf) / (fabs(mt) + 1e-8);
    return closs + vloss + mloss;
}

// ---------------------------------------------------------------------------
struct PatchCfg {
    int P[3], nseg[3], rs[3];
    float rp[3];          // 1/P for exact boundary division (fused path)
    bool vp[3], hr[3];
};

__device__ __forceinline__ void make_cfg(int fr0, int fr1, int fr2, PatchCfg& c) {
    c.P[0] = idiv336(fr0); c.P[1] = idiv336(fr1); c.P[2] = idiv336(fr2);
    c.vp[0] = (c.P[0] >= 5);
    c.vp[1] = (c.P[1] >= 5) && (c.P[1] != c.P[0]);
    c.vp[2] = (c.P[2] >= 5) && (c.P[2] != c.P[0]) && (c.P[2] != c.P[1]);
#pragma unroll
    for (int q = 0; q < 3; q++) {
        c.nseg[q] = idiv336(c.P[q] > 0 ? c.P[q] : 1);
        c.rs[q] = c.nseg[q] * c.P[q];
        c.hr[q] = c.vp[q] && ((TT - c.rs[q]) >= 5);
        c.rp[q] = (c.P[q] > 0) ? __frcp_rn((float)c.P[q]) : 0.0f;
    }
}

// slot i in [0,204) -> (s,e,kept) with dedup against earlier periods
__device__ __forceinline__ bool slot_patch(const PatchCfg& c, int i, int& s, int& e) {
    bool kept = false;
    s = 0; e = 0;
    if (i < 204) {
        int k = (i >= 136) ? 2 : ((i >= 68) ? 1 : 0);
        int si = i - k * 68;
        if (c.vp[k]) {
            if (si < c.nseg[k]) { s = c.P[k] * si; e = s + c.P[k]; kept = true; }
            else if (si == c.nseg[k] && c.hr[k]) { s = c.rs[k]; e = TT; kept = true; }
            if (kept) {
#pragma unroll
                for (int j = 0; j < 2; j++) {
                    if (j < k && c.vp[j]) {
                        bool dup = (s == c.rs[j]) && (e == TT) && c.hr[j];
                        int len = e - s;
                        if (len == c.P[j] && s < c.rs[j] && (s % c.P[j]) == 0) dup = true;
                        if (dup) kept = false;
                    }
                }
            }
        }
    }
    return kept;
}

// ---------------------------------------------------------------------------
// Round-21 FUSED kernel: 512 threads, 16 series, 3 blocks/CU (24 waves).
// LDS squeezed under 160/3 KB:
//   ts  [16][338] float2  43264B   (phase T tables overlay rows IN PLACE)
//   sA  [16][340] ushort  10880B   (tk3/tkf/wls/wlc overlay after MFMA barrier)
//   wms double[8]            64B
// K-tail handled by a masked ks=10 MFMA (quad>=2 A-fragment zeroed; Wb rows
// are zero in [336,352)) instead of padding sA to 352.
// Epilogue: last-block final reduction (blkout + threadfence + counter) —
// deletes the reduce3 launch.
// ---------------------------------------------------------------------------
__global__ __launch_bounds__(512, 6) void fused_k(const float* __restrict__ tgO,
                                                  const float* __restrict__ fcO,
                                                  const unsigned short* __restrict__ Wb,
                                                  double* __restrict__ blkout,
                                                  unsigned* __restrict__ cnt,
                                                  float* __restrict__ out) {
    __shared__ __align__(16) char smem[43264 + 10880 + 64];
    float2* ts = (float2*)smem;                                  // [16][TSP]
    unsigned short* sA = (unsigned short*)(smem + 43264);        // [16][LDA2]
    ULL* tk3 = (ULL*)(smem + 43264);               // overlay: [8][16][3] = 3072
    uint4* tkf = (uint4*)(smem + 43264 + 3072);    // 256
    double* wls = (double*)(smem + 43264 + 3328);  // 64
    int* wlc = (int*)(smem + 43264 + 3392);        // 32
    int* isLast = (int*)(smem + 43264 + 3424);     // 4
    double* wms = (double*)(smem + 43264 + 10880); // 64 (separate: spans kernel)
    double* red = (double*)smem;                   // last-block scratch (ts dead)

    const int tid = threadIdx.x;
    const int wave = tid >> 6, lane = tid & 63;
    const int lb = (blockIdx.x & 7) * 161 + (blockIdx.x >> 3);
    if (lb >= NFB) return;
    const int serBase = lb * SPP;

    // ---- phase L: load (16 consecutive series = full 64B lines) ----
    {
        const int j = tid & 15, tch = tid >> 4;   // 32 t-chunks (16x11 + 16x10)
        const int ser = serBase + j;
        const int bb = ser / NF, ff = ser - bb * NF;
        const float* tb_ = tgO + (size_t)bb * TT * NF + ff;
        const float* fb_ = fcO + (size_t)bb * TT * NF + ff;
        int t0, nT;
        if (tch < 16) { t0 = tch * 11; nT = 11; }
        else          { t0 = 176 + (tch - 16) * 10; nT = 10; }
        float va[11], vc[11];
#pragma unroll
        for (int i = 0; i < 11; i++) if (i < nT) va[i] = tb_[(size_t)(t0 + i) * NF];
#pragma unroll
        for (int i = 0; i < 11; i++) if (i < nT) vc[i] = fb_[(size_t)(t0 + i) * NF];
        float ms = 0.0f;
#pragma unroll
        for (int i = 0; i < 11; i++) {
            if (i < nT) {
                int t = t0 + i;
                ts[j * TSP + t] = make_float2(va[i], vc[i]);
                sA[j * LDA2 + t] = f2bf(va[i]);
                float d = va[i] - vc[i];
                ms = fmaf(d, d, ms);
            }
        }
        for (int off = 32; off; off >>= 1) ms += __shfl_down(ms, off, 64);
        if (lane == 0) wms[wave] = (double)ms;
    }
    __syncthreads();

    // ---- phase P: PSD + top-3 via MFMA (masked K-tail) ----
    const int quad = lane >> 4, c = lane & 15;
    ULL t0k[4] = {0, 0, 0, 0}, t1k[4] = {0, 0, 0, 0}, t2k[4] = {0, 0, 0, 0};
    {
        const unsigned short* aRow = sA + c * LDA2 + quad * 8;
        // 21 nt tiles over 8 waves: waves 0-4 get 3, waves 5-7 get 2
        const int ntStart = (wave < 5) ? wave * 3 : 15 + (wave - 5) * 2;
        const int ntEnd = ntStart + ((wave < 5) ? 3 : 2);

        for (int nt = ntStart; nt < ntEnd; nt++) {
            const unsigned short* bRow = Wb + (size_t)(nt * 16 + c) * KP + quad * 8;
            f32x4 acc = (f32x4){0.f, 0.f, 0.f, 0.f};
#pragma unroll
            for (int ks = 0; ks < 10; ks++) {
                bf16x8 a = *(const bf16x8*)(aRow + ks * 32);
                bf16x8 b = *(const bf16x8*)(bRow + ks * 32);
                acc = __builtin_amdgcn_mfma_f32_16x16x32_bf16(a, b, acc, 0, 0, 0);
            }
            // tail ks=10: k in [320,352); quads 2,3 (k>=336) contribute zero.
            // Wb rows are zero there; A must be zeroed (pad LDS is garbage).
            {
                bf16x8 a10 = (bf16x8){0, 0, 0, 0, 0, 0, 0, 0};
                if (quad < 2) a10 = *(const bf16x8*)(aRow + 320);
                bf16x8 b10 = *(const bf16x8*)(bRow + 320);
                acc = __builtin_amdgcn_mfma_f32_16x16x32_bf16(a10, b10, acc, 0, 0, 0);
            }
            int n = nt * 16 + c;
            unsigned fidx = (unsigned)((n >> 1) + 1);
            unsigned ftag = 0xFFFFFFFFu - fidx;
            bool odd = (n & 1) != 0;
#pragma unroll
            for (int r = 0; r < 4; r++) {
                float v = acc[r];
                float p = v * v;
                p += __shfl_xor(p, 1, 64);            // pair cos/sin columns
                ULL key = odd ? 0ull
                              : (((ULL)__float_as_uint(p) << 32) | (ULL)ftag);
                ins3(t0k[r], t1k[r], t2k[r], key);
            }
        }
#pragma unroll
        for (int m = 2; m <= 8; m <<= 1) {
#pragma unroll
            for (int r = 0; r < 4; r++) {
                ULL b0 = __shfl_xor(t0k[r], m, 64);
                ULL b1 = __shfl_xor(t1k[r], m, 64);
                ULL b2 = __shfl_xor(t2k[r], m, 64);
                ins3(t0k[r], t1k[r], t2k[r], b0);
                ins3(t0k[r], t1k[r], t2k[r], b1);
                ins3(t0k[r], t1k[r], t2k[r], b2);
            }
        }
    }
    __syncthreads();   // ALL MFMAs done -> sA dead, tk3 may overlay it
    if (c == 0) {
#pragma unroll
        for (int r = 0; r < 4; r++) {
            int s = quad * 4 + r;
            tk3[(wave * 16 + s) * 3 + 0] = t0k[r];
            tk3[(wave * 16 + s) * 3 + 1] = t1k[r];
            tk3[(wave * 16 + s) * 3 + 2] = t2k[r];
        }
    }
    __syncthreads();
    if (tid < SPP) {
        ULL k0 = 0, k1 = 0, k2 = 0;
#pragma unroll
        for (int wv = 0; wv < WV; wv++) {
#pragma unroll
            for (int j = 0; j < 3; j++) ins3(k0, k1, k2, tk3[(wv * 16 + tid) * 3 + j]);
        }
        unsigned f0 = 0xFFFFFFFFu - (unsigned)(k0 & 0xFFFFFFFFull);
        unsigned f1 = 0xFFFFFFFFu - (unsigned)(k1 & 0xFFFFFFFFull);
        unsigned f2 = 0xFFFFFFFFu - (unsigned)(k2 & 0xFFFFFFFFull);
        tkf[tid] = make_uint4(f0, f1, f2, 0u);
    }
    __syncthreads();

    // ---- phase T: 2 serial series/wave; tables overlay own ts rows ----
    // Prefetch BOTH series' elements first (the table writes destroy them).
    float* tw = (float*)smem + (size_t)(wave * 2) * (TSP * 2);  // 2 rows=5408B
    float2 lcA[6], lcB[6];
    if (lane < 56) {
        const float4* p0 = (const float4*)(ts + (wave * 2) * TSP + 6 * lane);
        const float4* p1 = (const float4*)(ts + (wave * 2 + 1) * TSP + 6 * lane);
        float4 a0 = p0[0], a1 = p0[1], a2 = p0[2];
        float4 b0 = p1[0], b1 = p1[1], b2 = p1[2];
        lcA[0] = make_float2(a0.x, a0.y); lcA[1] = make_float2(a0.z, a0.w);
        lcA[2] = make_float2(a1.x, a1.y); lcA[3] = make_float2(a1.z, a1.w);
        lcA[4] = make_float2(a2.x, a2.y); lcA[5] = make_float2(a2.z, a2.w);
        lcB[0] = make_float2(b0.x, b0.y); lcB[1] = make_float2(b0.z, b0.w);
        lcB[2] = make_float2(b1.x, b1.y); lcB[3] = make_float2(b1.z, b1.w);
        lcB[4] = make_float2(b2.x, b2.y); lcB[5] = make_float2(b2.z, b2.w);
    }

    float lsum = 0.0f;
    int lcnt = 0;
#pragma unroll 1
    for (int r = 0; r < 2; r++) {
        const int jj = (wave << 1) | r;

        uint4 tk = tkf[jj];
        PatchCfg cfg;
        make_cfg((int)tk.x, (int)tk.y, (int)tk.z, cfg);

        float2 loc[6];
#pragma unroll
        for (int i = 0; i < 6; i++) loc[i] = r ? lcB[i] : lcA[i];

        float c1 = 0.f, c2 = 0.f, c3 = 0.f, c4 = 0.f, c5 = 0.f;
        if (lane < 56) {
#pragma unroll
            for (int i = 0; i < 6; i++) {
                float a = loc[i].x, b = loc[i].y;
                c1 += a; c2 += b;
                c3 = fmaf(a, a, c3); c4 = fmaf(b, b, c4); c5 = fmaf(a, b, c5);
            }
        }

        float s1 = c1, s2 = c2, s3 = c3, s4 = c4, s5 = c5;
#pragma unroll
        for (int off = 1; off < 64; off <<= 1) {
            float y1 = __shfl_up(s1, off, 64);
            float y2 = __shfl_up(s2, off, 64);
            float y3 = __shfl_up(s3, off, 64);
            float y4 = __shfl_up(s4, off, 64);
            float y5 = __shfl_up(s5, off, 64);
            if (lane >= off) { s1 += y1; s2 += y2; s3 += y3; s4 += y4; s5 += y5; }
        }

        // table init: prefix[0] = 0 for all three periods
        if (lane == 63) {
#pragma unroll
            for (int k = 0; k < 3; k++) {
#pragma unroll
                for (int q = 0; q < 5; q++) tw[(k * 70) * 5 + q] = 0.f;
            }
        }
        // boundary writes: position t' = 6*lane+i+1; write prefix to
        // tab[k][t'/P] when P | t'; t'=336 writes totals.
        if (lane < 56) {
            float r1 = s1 - c1, r2 = s2 - c2;
            float r3 = s3 - c3, r4 = s4 - c4, r5 = s5 - c5;
#pragma unroll
            for (int i = 0; i < 6; i++) {
                float a = loc[i].x, b = loc[i].y;
                r1 += a; r2 += b;
                r3 = fmaf(a, a, r3); r4 = fmaf(b, b, r4); r5 = fmaf(a, b, r5);
                int tp = 6 * lane + i + 1;
                float tpf = (float)tp;
                if (tp == TT) {
                    tw[1050] = r1; tw[1051] = r2; tw[1052] = r3;
                    tw[1053] = r4; tw[1054] = r5;
                }
#pragma unroll
                for (int k = 0; k < 3; k++) {
                    if (cfg.vp[k]) {
                        int q = (int)(tpf * cfg.rp[k] + 0.001f);
                        if (q * cfg.P[k] == tp && q <= 68) {
                            int ix = (k * 70 + q) * 5;
                            tw[ix + 0] = r1; tw[ix + 1] = r2; tw[ix + 2] = r3;
                            tw[ix + 3] = r4; tw[ix + 4] = r5;
                        }
                    }
                }
            }
        }
        // wave-private table: no __syncthreads; per-wave lgkm ordering suffices.

        ULL anyMask = 0ull;
#pragma unroll
        for (int rI = 0; rI < 4; rI++) {
            int i = lane + 64 * rI;
            int s, e;
            bool kept = slot_patch(cfg, i, s, e);
            ULL bal = __ballot(kept);
            anyMask |= bal;
            if (bal == 0ull) continue;          // wave-uniform early-out
            if (kept) {
                int k = (i >= 136) ? 2 : ((i >= 68) ? 1 : 0);
                int si = i - k * 68;
                bool tail = (si == cfg.nseg[k]);
                const float* pS = tw + (k * 70 + si) * 5;
                const float* pE = tail ? (tw + 1050) : (tw + (k * 70 + si + 1) * 5);
                float S1 = pE[0] - pS[0];
                float S2 = pE[1] - pS[1];
                float S3 = pE[2] - pS[2];
                float S4 = pE[3] - pS[3];
                float S5 = pE[4] - pS[4];
                lsum += patch_loss_f32(S1, S2, S3, S4, S5, e - s);
                lcnt += 1;
            }
        }
        if (anyMask == 0ull) {
            if (lane == 0) {
                lsum += patch_loss_f32(tw[1050], tw[1051], tw[1052],
                                       tw[1053], tw[1054], TT);
                lcnt += 1;
            }
        }
    }

    for (int off = 32; off; off >>= 1) {
        lsum += __shfl_down(lsum, off, 64);
        lcnt += __shfl_down(lcnt, off, 64);
    }
    if (lane == 0) { wls[wave] = (double)lsum; wlc[wave] = lcnt; }
    __syncthreads();
    if (tid == 0) {
        double L = 0.0, M = 0.0;
        int C = 0;
#pragma unroll
        for (int wv = 0; wv < WV; wv++) { L += wls[wv]; C += wlc[wv]; M += wms[wv]; }
        blkout[3 * lb + 0] = L;
        blkout[3 * lb + 1] = (double)C;
        blkout[3 * lb + 2] = M;
        __threadfence();
        unsigned old = atomicAdd(cnt, 1u);
        *isLast = (old == (unsigned)(NFB - 1)) ? 1 : 0;
    }
    __syncthreads();

    // ---- last block performs the final reduction (reduce3 fold-in) ----
    if (*isLast) {
        __threadfence();
        double ls = 0.0, lc2 = 0.0, ms2 = 0.0;
        for (int i = tid; i < NFB; i += 512) {
            ls += blkout[3 * i + 0];
            lc2 += blkout[3 * i + 1];
            ms2 += blkout[3 * i + 2];
        }
        for (int off = 32; off; off >>= 1) {
            ls += __shfl_down(ls, off, 64);
            lc2 += __shfl_down(lc2, off, 64);
            ms2 += __shfl_down(ms2, off, 64);
        }
        if (lane == 0) { red[wave] = ls; red[8 + wave] = lc2; red[16 + wave] = ms2; }
        __syncthreads();
        if (tid == 0) {
            double L = 0, C = 0, M = 0;
#pragma unroll
            for (int i = 0; i < 8; i++) { L += red[i]; C += red[8 + i]; M += red[16 + i]; }
            double mse = M / (double)((size_t)NB * TT * NF);
            double avg = (C > 0.0) ? (L / C) : 0.0;
            out[0] = (float)(0.5 * mse + 0.5 * avg);
        }
    }
}

// ---------------------------------------------------------------------------
// FALLBACK Kernel: transpose [B,T,F] -> float2{tg,fc}[B*F][T], fused MSE.
// ---------------------------------------------------------------------------
__global__ __launch_bounds__(256) void transpose_k(const float* __restrict__ fc,
                                                   const float* __restrict__ tg,
                                                   float2* __restrict__ out,
                                                   double* __restrict__ msep,
                                                   double* __restrict__ acc) {
    __shared__ float ta[32][33];
    __shared__ float tb[32][33];
    __shared__ double wacc[4];
    const int b = blockIdx.z;
    const int t0 = blockIdx.x * 32, f0 = blockIdx.y * 32;
    const int tx = threadIdx.x, ty = threadIdx.y;   // block (32, 8)
    const size_t base = (size_t)b * TT * NF;
    double ms = 0.0;
#pragma unroll
    for (int k = 0; k < 4; k++) {
        int t = t0 + ty + 8 * k, f = f0 + tx;
        if (t < TT && f < NF) {
            float a = tg[base + (size_t)t * NF + f];
            float c = fc[base + (size_t)t * NF + f];
            ta[ty + 8 * k][tx] = a;
            tb[ty + 8 * k][tx] = c;
            double d = (double)a - (double)c;
            ms += d * d;
        }
    }
    __syncthreads();
#pragma unroll
    for (int k = 0; k < 4; k++) {
        int f = f0 + ty + 8 * k, t = t0 + tx;
        if (t < TT && f < NF) {
            out[((size_t)b * NF + f) * TT + t] =
                make_float2(ta[tx][ty + 8 * k], tb[tx][ty + 8 * k]);
        }
    }
    for (int off = 32; off; off >>= 1) ms += __shfl_down(ms, off, 64);
    int flat = ty * 32 + tx;
    int lane = flat & 63, wid = flat >> 6;
    if (lane == 0) wacc[wid] = ms;
    __syncthreads();
    if (flat == 0) {
        double tot = wacc[0] + wacc[1] + wacc[2] + wacc[3];
        if (msep) {
            int blk = (blockIdx.z * TGY + blockIdx.y) * TGX + blockIdx.x;
            msep[blk] = tot;
        } else {
            atomicAdd(&acc[0], tot);
        }
    }
}

// ---------------------------------------------------------------------------
__global__ void mse_k(const float* __restrict__ fc, const float* __restrict__ tg,
                      double* __restrict__ acc) {
    const size_t N4 = (size_t)NB * TT * NF / 4;
    const float4* a4 = (const float4*)fc;
    const float4* b4 = (const float4*)tg;
    double s = 0.0;
    for (size_t i = (size_t)blockIdx.x * blockDim.x + threadIdx.x; i < N4;
         i += (size_t)gridDim.x * blockDim.x) {
        float4 a = a4[i], b = b4[i];
        double d0 = (double)a.x - (double)b.x;
        double d1 = (double)a.y - (double)b.y;
        double d2 = (double)a.z - (double)b.z;
        double d3 = (double)a.w - (double)b.w;
        s += d0 * d0 + d1 * d1 + d2 * d2 + d3 * d3;
    }
    for (int off = 32; off; off >>= 1) s += __shfl_down(s, off, 64);
    __shared__ double wsum[4];
    int flat = threadIdx.x;
    int lane = flat & 63, wid = flat >> 6;
    if (lane == 0) wsum[wid] = s;
    __syncthreads();
    if (flat == 0) atomicAdd(&acc[0], wsum[0] + wsum[1] + wsum[2] + wsum[3]);
}

// ---------------------------------------------------------------------------
// FALLBACK: self-contained series kernel (VALU DFT + topk + serial patches).
// ---------------------------------------------------------------------------
__device__ __forceinline__ void patch_body(const float2* tsw, int lane,
                                           int fr0, int fr1, int fr2,
                                           double& lsum, double& lcnt) {
    PatchCfg cfg;
    make_cfg(fr0, fr1, fr2, cfg);
    ULL anyMask = 0ull;
#pragma unroll
    for (int rI = 0; rI < 4; rI++) {
        int s, e;
        bool kept = slot_patch(cfg, lane + 64 * rI, s, e);
        anyMask |= __ballot(kept);
        if (kept) {
            double S1 = 0, S2 = 0, S3 = 0, S4 = 0, S5 = 0;
            for (int t = s; t < e; t++) {
                float2 v = tsw[t];
                double a = (double)v.x, b = (double)v.y;
                S1 += a; S2 += b;
                S3 += a * a; S4 += b * b; S5 += a * b;
            }
            lsum += patch_loss(S1, S2, S3, S4, S5, (double)(e - s));
            lcnt += 1.0;
        }
    }
    if (anyMask == 0ull) {
        double S1 = 0, S2 = 0, S3 = 0, S4 = 0, S5 = 0;
        for (int t = lane; t < TT; t += 64) {
            float2 v = tsw[t];
            double a = (double)v.x, b = (double)v.y;
            S1 += a; S2 += b;
            S3 += a * a; S4 += b * b; S5 += a * b;
        }
        for (int off = 32; off; off >>= 1) {
            S1 += __shfl_down(S1, off, 64);
            S2 += __shfl_down(S2, off, 64);
            S3 += __shfl_down(S3, off, 64);
            S4 += __shfl_down(S4, off, 64);
            S5 += __shfl_down(S5, off, 64);
        }
        if (lane == 0) {
            lsum += patch_loss(S1, S2, S3, S4, S5, (double)TT);
            lcnt += 1.0;
        }
    }
}

__global__ __launch_bounds__(256, 6) void series_k(const float2* __restrict__ tsG,
                                                   const float* __restrict__ fcG,
                                                   const float* __restrict__ tgG,
                                                   int transposed,
                                                   double2* __restrict__ pairs,
                                                   double* __restrict__ acc) {
    const int w = threadIdx.x >> 6, lane = threadIdx.x & 63;
    const int ser = blockIdx.x * WPB + w;
    __shared__ float2 ts[WPB][TT];
    __shared__ float4 zb[WPB][84];

    if (transposed) {
        const float2* sp = tsG + (size_t)ser * TT;
        for (int t = lane; t < TT; t += 64) ts[w][t] = sp[t];
    } else {
        int b = ser / NF, f = ser - b * NF;
        const float* tp = tgG + (size_t)b * TT * NF + f;
        const float* fp = fcG + (size_t)b * TT * NF + f;
        for (int t = lane; t < TT; t += 64)
            ts[w][t] = make_float2(tp[(size_t)t * NF], fp[(size_t)t * NF]);
    }
    __syncthreads();

    for (int t = lane; t < 84; t += 64) {
        float x0 = ts[w][t].x, x1 = ts[w][t + 84].x;
        float x2 = ts[w][t + 168].x, x3 = ts[w][t + 252].x;
        float a = x0 + x2, b2 = x1 + x3, c = x0 - x2, d = x1 - x3;
        zb[w][t] = make_float4(a + b2, a - b2, c, d);
    }
    __syncthreads();

    const double TWOPI = 6.283185307179586476925286766559;
    int fb[3] = {1 + lane, 65 + lane, 129 + lane};
    float cc[3], sn[3], re[3], im[3], cd[3], sd[3], sgn[3];
    int selA[3];
#pragma unroll
    for (int q = 0; q < 3; q++) {
        int f = fb[q], cls = f & 3;
        double dl = (double)f * (TWOPI / 336.0);
        cd[q] = (float)cos(dl);
        sd[q] = (float)sin(dl);
        cc[q] = 1.0f; sn[q] = 0.0f; re[q] = 0.0f; im[q] = 0.0f;
        sgn[q] = (cls == 1) ? -1.0f : ((cls == 3) ? 1.0f : 0.0f);
        selA[q] = (cls == 0) ? 0 : ((cls == 2) ? 1 : 2);
    }
    for (int t = 0; t < 84; t++) {
        float4 zv = zb[w][t];
#pragma unroll
        for (int q = 0; q < 3; q++) {
            float zr = (selA[q] == 0) ? zv.x : ((selA[q] == 1) ? zv.y : zv.z);
            float zi = sgn[q] * zv.w;
            re[q] = fmaf(zr, cc[q], re[q]);
            re[q] = fmaf(zi, sn[q], re[q]);
            im[q] = fmaf(zi, cc[q], im[q]);
            im[q] = fmaf(-zr, sn[q], im[q]);
            float nc = fmaf(cc[q], cd[q], -(sn[q] * sd[q]));
            float ns = fmaf(sn[q], cd[q], cc[q] * sd[q]);
            cc[q] = nc; sn[q] = ns;
        }
    }

    ULL k0 = 0, k1 = 0, k2 = 0;
#pragma unroll
    for (int q = 0; q < 3; q++) {
        float a2 = fmaf(re[q], re[q], im[q] * im[q]);
        ULL key = ((ULL)__float_as_uint(a2) << 32) |
                  (ULL)(0xFFFFFFFFu - (unsigned)fb[q]);
        if (fb[q] > 168) key = 0ull;
        ins3(k0, k1, k2, key);
    }
    for (int m = 1; m < 64; m <<= 1) {
        ULL b0 = __shfl_xor(k0, m, 64);
        ULL b1 = __shfl_xor(k1, m, 64);
        ULL b2 = __shfl_xor(k2, m, 64);
        ins3(k0, k1, k2, b0); ins3(k0, k1, k2, b1); ins3(k0, k1, k2, b2);
    }

    int fr0 = (int)(0xFFFFFFFFu - (unsigned)(k0 & 0xFFFFFFFFull));
    int fr1 = (int)(0xFFFFFFFFu - (unsigned)(k1 & 0xFFFFFFFFull));
    int fr2 = (int)(0xFFFFFFFFu - (unsigned)(k2 & 0xFFFFFFFFull));

    double lsum = 0.0, lcnt = 0.0;
    patch_body(&ts[w][0], lane, fr0, fr1, fr2, lsum, lcnt);

    for (int off = 32; off; off >>= 1) {
        lsum += __shfl_down(lsum, off, 64);
        lcnt += __shfl_down(lcnt, off, 64);
    }
    if (lane == 0) {
        if (pairs) {
            pairs[ser] = make_double2(lsum, lcnt);
        } else {
            atomicAdd(&acc[1], lsum);
            atomicAdd(&acc[2], lcnt);
        }
    }
}

// fallback reduce over pairs+msep (round-3 style)
__global__ __launch_bounds__(1024) void reduce_k(const double2* __restrict__ pairs,
                                                 const double* __restrict__ msep,
                                                 int nmse,
                                                 float* __restrict__ out) {
    const int tid = threadIdx.x;
    double ls = 0.0, lc = 0.0, ms = 0.0;
    for (int i = tid; i < NSER; i += 1024) {
        double2 p = pairs[i];
        ls += p.x; lc += p.y;
    }
    for (int i = tid; i < nmse; i += 1024) ms += msep[i];
    for (int off = 32; off; off >>= 1) {
        ls += __shfl_down(ls, off, 64);
        lc += __shfl_down(lc, off, 64);
        ms += __shfl_down(ms, off, 64);
    }
    __shared__ double sl[16], sc[16], sm[16];
    int lane = tid & 63, wid = tid >> 6;
    if (lane == 0) { sl[wid] = ls; sc[wid] = lc; sm[wid] = ms; }
    __syncthreads();
    if (tid == 0) {
        double L = 0, C = 0, M = 0;
        for (int i = 0; i < 16; i++) { L += sl[i]; C += sc[i]; M += sm[i]; }
        double mse = M / (double)((size_t)NB * TT * NF);
        double avg = (C > 0.0) ? (L / C) : 0.0;
        out[0] = (float)(0.5 * mse + 0.5 * avg);
    }
}

__global__ void finalize_k(const double* __restrict__ acc, float* __restrict__ out) {
    double mse = acc[0] / (double)((size_t)NB * TT * NF);
    double avg = (acc[2] > 0.0) ? (acc[1] / acc[2]) : 0.0;
    out[0] = (float)(0.5 * mse + 0.5 * avg);
}

// ---------------------------------------------------------------------------
extern "C" void kernel_launch(void* const* d_in, const int* in_sizes, int n_in,
                              void* d_out, int out_size, void* d_ws, size_t ws_size,
                              hipStream_t stream) {
    const float* fc = (const float*)d_in[0];   // forecast
    const float* tg = (const float*)d_in[1];   // target
    float* out = (float*)d_out;
    char* ws = (char*)d_ws;
    double* acc = (double*)ws;
    unsigned* cnt = (unsigned*)(ws + 32);      // big2: block-completion counter

    // layout: [0,64) acc/cnt | msep | blkout/pairs | (unused topk) | Wb | (fb tsT)
    const size_t OFF_MSE = 64;
    const size_t OFF_PAIR = OFF_MSE + (size_t)NMSEP * sizeof(double);        // 62016
    const size_t OFF_TOP = OFF_PAIR + (size_t)NSER * sizeof(double2);        // 390720
    const size_t OFF_W = OFF_TOP + (size_t)NSER * sizeof(uint4);             // 719424
    const size_t OFF_END2 = OFF_W + (size_t)TT * KP * sizeof(unsigned short);// 955968
    const size_t bytesT = (size_t)NSER * TT * sizeof(float2);
    const bool big2 = (ws_size >= OFF_END2);                   // main path
    const size_t R3_OFF_TS = OFF_PAIR + (size_t)NSER * sizeof(double2);
    const bool big = !big2 && (ws_size >= R3_OFF_TS + bytesT);
    const bool mid = !big2 && !big && (ws_size >= OFF_MSE + bytesT);

    double* msep = (double*)(ws + OFF_MSE);
    double* blkout = (double*)(ws + OFF_PAIR);   // 3*NFB doubles (31 KB)
    unsigned short* Wb = (unsigned short*)(ws + OFF_W);

    dim3 tg_grid(TGX, TGY, NB);
    dim3 tg_blk(32, 8);

    if (big2) {
        hipMemsetAsync(d_ws, 0, 64, stream);     // zero acc + counter
        twiddle_k<<<TT, 128, 0, stream>>>(Wb);
        fused_k<<<NFBG, 64 * WV, 0, stream>>>(tg, fc, Wb, blkout, cnt, out);
    } else if (big) {
        float2* tsT = (float2*)(ws + R3_OFF_TS);
        transpose_k<<<tg_grid, tg_blk, 0, stream>>>(fc, tg, tsT, msep, acc);
        series_k<<<NSER / WPB, 64 * WPB, 0, stream>>>(tsT, fc, tg, 1,
                                                      (double2*)blkout, acc);
        reduce_k<<<1, 1024, 0, stream>>>((double2*)blkout, msep, NMSEP, out);
    } else if (mid) {
        float2* tsT = (float2*)(ws + OFF_MSE);
        hipMemsetAsync(d_ws, 0, 64, stream);
        transpose_k<<<tg_grid, tg_blk, 0, stream>>>(fc, tg, tsT, nullptr, acc);
        series_k<<<NSER / WPB, 64 * WPB, 0, stream>>>(tsT, fc, tg, 1, nullptr, acc);
        finalize_k<<<1, 1, 0, stream>>>(acc, out);
    } else {
        hipMemsetAsync(d_ws, 0, 64, stream);
        mse_k<<<1024, 256, 0, stream>>>(fc, tg, acc);
        series_k<<<NSER / WPB, 64 * WPB, 0, stream>>>(nullptr, fc, tg, 0, nullptr, acc);
        finalize_k<<<1, 1, 0, stream>>>(acc, out);
    }
}

// Round 7
// 200.822 us; speedup vs baseline: 1.4098x; 1.4098x over previous
//
#include <hip/hip_runtime.h>
#include <hip/hip_bf16.h>

#define TT 336
#define NF 321
#define NB 64
#define NSER (NB * NF)   // 20544 series
#define WPB 4            // waves (series) per block in FALLBACK series kernel
#define KP 352           // Wb row stride (zero-padded tail k in [336,352))
#define LDA2 340         // sA row stride (ushorts): 680B = 170 words == 10 mod 32
                         // -> 16-lane write pattern hits 16 distinct banks
#define SPP 16           // series per fused block (64B line = 16 floats)
#define WV 8             // waves per fused block (512 threads)
#define NFB (NSER / SPP)     // 1284 fused blocks
#define NFBG 1288            // dispatched (8 x 161, guard skips 4)
#define TSP 338          // ts row stride float2: 2704B == 16 mod 128 -> 2-way free

// per-wave boundary tables overlay the wave's own 2 consumed ts rows:
// [3 periods][70 slots][5 stats] + totals[5] = 4224B <= 2*2704B
#define TWS 1056

// transpose grid (fallback paths): 11 x 11 x 64 blocks
#define TGX 11
#define TGY 11
#define NMSEP (TGX * TGY * NB)   // 7744 per-block MSE partials (fallback)

typedef __attribute__((ext_vector_type(8))) short bf16x8;
typedef __attribute__((ext_vector_type(4))) float f32x4;
typedef unsigned long long ULL;

__device__ __forceinline__ unsigned short f2bf(float v) {
    unsigned x = __float_as_uint(v);
    x += 0x7FFFu + ((x >> 16) & 1u);   // RNE; inputs are finite
    return (unsigned short)(x >> 16);
}

// sorted-3 insert (a0 >= a1 >= a2)
__device__ __forceinline__ void ins3(ULL& a0, ULL& a1, ULL& a2, ULL x) {
    ULL hi = a0 > x ? a0 : x;
    ULL lo = a0 > x ? x : a0;
    a0 = hi;
    ULL hi1 = a1 > lo ? a1 : lo;
    ULL lo1 = a1 > lo ? lo : a1;
    a1 = hi1;
    a2 = a2 > lo1 ? a2 : lo1;
}

// exact integer 336/d via fast fp32 division (error ~1e-7 rel, 100x margin
// to the 1/336 distance from integer boundaries). d>336 (garbage) -> 0.
__device__ __forceinline__ int idiv336(int d) {
    return (int)(__fdividef(336.0f, (float)d));
}

// ---------------------------------------------------------------------------
// Twiddle matrix: Wb[n][k], n=2(f-1) -> cos(2pi f k/336), n=2(f-1)+1 -> sin.
// Tail k in [336,352) is ZERO — the fused kernel's masked tail MFMA relies
// on it.
// ---------------------------------------------------------------------------
__global__ void twiddle_k(unsigned short* __restrict__ Wb) {
    int n = blockIdx.x;          // 0..335
    int f = (n >> 1) + 1;
    int isSin = n & 1;
    for (int k = threadIdx.x; k < KP; k += blockDim.x) {
        float v = 0.0f;
        if (k < TT) {
            int r = (f * k) % TT;
            float ang = 6.2831853071795864769f * (float)r / 336.0f;
            v = isSin ? sinf(ang) : cosf(ang);
        }
        Wb[(size_t)n * KP + k] = f2bf(v);
    }
}

// ---------------------------------------------------------------------------
// All-fp32 patch loss (r16: matches the fp32 JAX reference; absmax 0.0625,
// deterministic, inside tolerance).
// ---------------------------------------------------------------------------
__device__ __forceinline__ float patch_loss_f32(float S1, float S2, float S3,
                                                float S4, float S5, int n) {
    float nnf = (float)n;
    float invf = 1.0f / nnf;
    float tvs = S3 - S1 * S1 * invf; tvs = tvs > 0.f ? tvs : 0.f;
    float fvs = S4 - S2 * S2 * invf; fvs = fvs > 0.f ? fvs : 0.f;
    float num = S5 - S1 * S2 * invf;
    float corr = num / (sqrtf(tvs * fvs) + 1e-8f);
    float closs = 1.0f - fabsf(corr);
    float vloss = fabsf(tvs - fvs) / (tvs + (nnf - 1.0f) * 1e-8f);
    float mloss = fabsf(S1 - S2) / (fabsf(S1) + nnf * 1e-8f);
    return closs + vloss + mloss;
}

// full-fp64 patch loss (fallback series kernel only)
__device__ __forceinline__ double patch_loss(double S1, double S2, double S3,
                                             double S4, double S5, double nn) {
    double mt = S1 / nn, mf = S2 / nn;
    double tvs = S3 - nn * mt * mt; tvs = tvs > 0.0 ? tvs : 0.0;
    double fvs = S4 - nn * mf * mf; fvs = fvs > 0.0 ? fvs : 0.0;
    double num = S5 - nn * mt * mf;
    double corr = num / (sqrt(tvs * fvs) + 1e-8);
    double closs = 1.0 - fabs(corr);
    double tvar = tvs / (nn - 1.0), fvar = fvs / (nn - 1.0);
    double vloss = fabs(tvar - fvar) / (tvar + 1e-8);
    double mloss = fabs(mt - mf) / (fabs(mt) + 1e-8);
    return closs + vloss + mloss;
}

// ---------------------------------------------------------------------------
struct PatchCfg {
    int P[3], nseg[3], rs[3];
    float rp[3];          // 1/P for exact boundary division (fused path)
    bool vp[3], hr[3];
};

__device__ __forceinline__ void make_cfg(int fr0, int fr1, int fr2, PatchCfg& c) {
    c.P[0] = idiv336(fr0); c.P[1] = idiv336(fr1); c.P[2] = idiv336(fr2);
    c.vp[0] = (c.P[0] >= 5);
    c.vp[1] = (c.P[1] >= 5) && (c.P[1] != c.P[0]);
    c.vp[2] = (c.P[2] >= 5) && (c.P[2] != c.P[0]) && (c.P[2] != c.P[1]);
#pragma unroll
    for (int q = 0; q < 3; q++) {
        c.nseg[q] = idiv336(c.P[q] > 0 ? c.P[q] : 1);
        c.rs[q] = c.nseg[q] * c.P[q];
        c.hr[q] = c.vp[q] && ((TT - c.rs[q]) >= 5);
        c.rp[q] = (c.P[q] > 0) ? __frcp_rn((float)c.P[q]) : 0.0f;
    }
}

// slot i in [0,204) -> (s,e,kept) with dedup against earlier periods
__device__ __forceinline__ bool slot_patch(const PatchCfg& c, int i, int& s, int& e) {
    bool kept = false;
    s = 0; e = 0;
    if (i < 204) {
        int k = (i >= 136) ? 2 : ((i >= 68) ? 1 : 0);
        int si = i - k * 68;
        if (c.vp[k]) {
            if (si < c.nseg[k]) { s = c.P[k] * si; e = s + c.P[k]; kept = true; }
            else if (si == c.nseg[k] && c.hr[k]) { s = c.rs[k]; e = TT; kept = true; }
            if (kept) {
#pragma unroll
                for (int j = 0; j < 2; j++) {
                    if (j < k && c.vp[j]) {
                        bool dup = (s == c.rs[j]) && (e == TT) && c.hr[j];
                        int len = e - s;
                        if (len == c.P[j] && s < c.rs[j] && (s % c.P[j]) == 0) dup = true;
                        if (dup) kept = false;
                    }
                }
            }
        }
    }
    return kept;
}

// ---------------------------------------------------------------------------
// Round-22 FUSED kernel: 512 threads, 16 series, 3 blocks/CU (24 waves).
// r21's ONLY error: __launch_bounds__(512,6) capped VGPR at 40 -> staging
// arrays spilled to scratch (WRITE_SIZE 0.03 -> 110MB, 224us). Natural
// allocation is ~56 VGPR (r20 measured), <=64, so 24 waves/CU needs NO cap.
// LDS plan (verified r21: LDS_Block_Size 54,272 -> 3 blocks/CU):
//   ts  [16][338] float2  43264B   (phase T tables overlay rows IN PLACE)
//   sA  [16][340] ushort  10880B   (tk3/tkf/wls/wlc overlay after MFMA barrier)
//   wms double[8]            64B
// K-tail via masked ks=10 MFMA (quad>=2 A zeroed; Wb zero in [336,352)).
// Epilogue: last-block final reduction — reduce3 launch deleted.
// ---------------------------------------------------------------------------
__global__ __launch_bounds__(512) void fused_k(const float* __restrict__ tgO,
                                               const float* __restrict__ fcO,
                                               const unsigned short* __restrict__ Wb,
                                               double* __restrict__ blkout,
                                               unsigned* __restrict__ cnt,
                                               float* __restrict__ out) {
    __shared__ __align__(16) char smem[43264 + 10880 + 64];
    float2* ts = (float2*)smem;                                  // [16][TSP]
    unsigned short* sA = (unsigned short*)(smem + 43264);        // [16][LDA2]
    ULL* tk3 = (ULL*)(smem + 43264);               // overlay: [8][16][3] = 3072
    uint4* tkf = (uint4*)(smem + 43264 + 3072);    // 256
    double* wls = (double*)(smem + 43264 + 3328);  // 64
    int* wlc = (int*)(smem + 43264 + 3392);        // 32
    int* isLast = (int*)(smem + 43264 + 3424);     // 4
    double* wms = (double*)(smem + 43264 + 10880); // 64 (separate: spans kernel)
    double* red = (double*)smem;                   // last-block scratch (ts dead)

    const int tid = threadIdx.x;
    const int wave = tid >> 6, lane = tid & 63;
    const int lb = (blockIdx.x & 7) * 161 + (blockIdx.x >> 3);
    if (lb >= NFB) return;
    const int serBase = lb * SPP;

    // ---- phase L: load (16 consecutive series = full 64B lines) ----
    {
        const int j = tid & 15, tch = tid >> 4;   // 32 t-chunks (16x11 + 16x10)
        const int ser = serBase + j;
        const int bb = ser / NF, ff = ser - bb * NF;
        const float* tb_ = tgO + (size_t)bb * TT * NF + ff;
        const float* fb_ = fcO + (size_t)bb * TT * NF + ff;
        int t0, nT;
        if (tch < 16) { t0 = tch * 11; nT = 11; }
        else          { t0 = 176 + (tch - 16) * 10; nT = 10; }
        float va[11], vc[11];
#pragma unroll
        for (int i = 0; i < 11; i++) if (i < nT) va[i] = tb_[(size_t)(t0 + i) * NF];
#pragma unroll
        for (int i = 0; i < 11; i++) if (i < nT) vc[i] = fb_[(size_t)(t0 + i) * NF];
        float ms = 0.0f;
#pragma unroll
        for (int i = 0; i < 11; i++) {
            if (i < nT) {
                int t = t0 + i;
                ts[j * TSP + t] = make_float2(va[i], vc[i]);
                sA[j * LDA2 + t] = f2bf(va[i]);
                float d = va[i] - vc[i];
                ms = fmaf(d, d, ms);
            }
        }
        for (int off = 32; off; off >>= 1) ms += __shfl_down(ms, off, 64);
        if (lane == 0) wms[wave] = (double)ms;
    }
    __syncthreads();

    // ---- phase P: PSD + top-3 via MFMA (masked K-tail) ----
    const int quad = lane >> 4, c = lane & 15;
    ULL t0k[4] = {0, 0, 0, 0}, t1k[4] = {0, 0, 0, 0}, t2k[4] = {0, 0, 0, 0};
    {
        const unsigned short* aRow = sA + c * LDA2 + quad * 8;
        // 21 nt tiles over 8 waves: waves 0-4 get 3, waves 5-7 get 2
        const int ntStart = (wave < 5) ? wave * 3 : 15 + (wave - 5) * 2;
        const int ntEnd = ntStart + ((wave < 5) ? 3 : 2);

        for (int nt = ntStart; nt < ntEnd; nt++) {
            const unsigned short* bRow = Wb + (size_t)(nt * 16 + c) * KP + quad * 8;
            f32x4 acc = (f32x4){0.f, 0.f, 0.f, 0.f};
#pragma unroll
            for (int ks = 0; ks < 10; ks++) {
                bf16x8 a = *(const bf16x8*)(aRow + ks * 32);
                bf16x8 b = *(const bf16x8*)(bRow + ks * 32);
                acc = __builtin_amdgcn_mfma_f32_16x16x32_bf16(a, b, acc, 0, 0, 0);
            }
            // tail ks=10: k in [320,352); quads 2,3 (k>=336) contribute zero.
            // Wb rows are zero there; A must be zeroed (pad LDS is garbage).
            {
                bf16x8 a10 = (bf16x8){0, 0, 0, 0, 0, 0, 0, 0};
                if (quad < 2) a10 = *(const bf16x8*)(aRow + 320);
                bf16x8 b10 = *(const bf16x8*)(bRow + 320);
                acc = __builtin_amdgcn_mfma_f32_16x16x32_bf16(a10, b10, acc, 0, 0, 0);
            }
            int n = nt * 16 + c;
            unsigned fidx = (unsigned)((n >> 1) + 1);
            unsigned ftag = 0xFFFFFFFFu - fidx;
            bool odd = (n & 1) != 0;
#pragma unroll
            for (int r = 0; r < 4; r++) {
                float v = acc[r];
                float p = v * v;
                p += __shfl_xor(p, 1, 64);            // pair cos/sin columns
                ULL key = odd ? 0ull
                              : (((ULL)__float_as_uint(p) << 32) | (ULL)ftag);
                ins3(t0k[r], t1k[r], t2k[r], key);
            }
        }
#pragma unroll
        for (int m = 2; m <= 8; m <<= 1) {
#pragma unroll
            for (int r = 0; r < 4; r++) {
                ULL b0 = __shfl_xor(t0k[r], m, 64);
                ULL b1 = __shfl_xor(t1k[r], m, 64);
                ULL b2 = __shfl_xor(t2k[r], m, 64);
                ins3(t0k[r], t1k[r], t2k[r], b0);
                ins3(t0k[r], t1k[r], t2k[r], b1);
                ins3(t0k[r], t1k[r], t2k[r], b2);
            }
        }
    }
    __syncthreads();   // ALL MFMAs done -> sA dead, tk3 may overlay it
    if (c == 0) {
#pragma unroll
        for (int r = 0; r < 4; r++) {
            int s = quad * 4 + r;
            tk3[(wave * 16 + s) * 3 + 0] = t0k[r];
            tk3[(wave * 16 + s) * 3 + 1] = t1k[r];
            tk3[(wave * 16 + s) * 3 + 2] = t2k[r];
        }
    }
    __syncthreads();
    if (tid < SPP) {
        ULL k0 = 0, k1 = 0, k2 = 0;
#pragma unroll
        for (int wv = 0; wv < WV; wv++) {
#pragma unroll
            for (int j = 0; j < 3; j++) ins3(k0, k1, k2, tk3[(wv * 16 + tid) * 3 + j]);
        }
        unsigned f0 = 0xFFFFFFFFu - (unsigned)(k0 & 0xFFFFFFFFull);
        unsigned f1 = 0xFFFFFFFFu - (unsigned)(k1 & 0xFFFFFFFFull);
        unsigned f2 = 0xFFFFFFFFu - (unsigned)(k2 & 0xFFFFFFFFull);
        tkf[tid] = make_uint4(f0, f1, f2, 0u);
    }
    __syncthreads();

    // ---- phase T: 2 serial series/wave; tables overlay own ts rows ----
    // Prefetch BOTH series' elements first (the table writes destroy them).
    float* tw = (float*)smem + (size_t)(wave * 2) * (TSP * 2);  // 2 rows=5408B
    float2 lcA[6], lcB[6];
    if (lane < 56) {
        const float4* p0 = (const float4*)(ts + (wave * 2) * TSP + 6 * lane);
        const float4* p1 = (const float4*)(ts + (wave * 2 + 1) * TSP + 6 * lane);
        float4 a0 = p0[0], a1 = p0[1], a2 = p0[2];
        float4 b0 = p1[0], b1 = p1[1], b2 = p1[2];
        lcA[0] = make_float2(a0.x, a0.y); lcA[1] = make_float2(a0.z, a0.w);
        lcA[2] = make_float2(a1.x, a1.y); lcA[3] = make_float2(a1.z, a1.w);
        lcA[4] = make_float2(a2.x, a2.y); lcA[5] = make_float2(a2.z, a2.w);
        lcB[0] = make_float2(b0.x, b0.y); lcB[1] = make_float2(b0.z, b0.w);
        lcB[2] = make_float2(b1.x, b1.y); lcB[3] = make_float2(b1.z, b1.w);
        lcB[4] = make_float2(b2.x, b2.y); lcB[5] = make_float2(b2.z, b2.w);
    }

    float lsum = 0.0f;
    int lcnt = 0;
#pragma unroll 1
    for (int r = 0; r < 2; r++) {
        const int jj = (wave << 1) | r;

        uint4 tk = tkf[jj];
        PatchCfg cfg;
        make_cfg((int)tk.x, (int)tk.y, (int)tk.z, cfg);

        float2 loc[6];
#pragma unroll
        for (int i = 0; i < 6; i++) loc[i] = r ? lcB[i] : lcA[i];

        float c1 = 0.f, c2 = 0.f, c3 = 0.f, c4 = 0.f, c5 = 0.f;
        if (lane < 56) {
#pragma unroll
            for (int i = 0; i < 6; i++) {
                float a = loc[i].x, b = loc[i].y;
                c1 += a; c2 += b;
                c3 = fmaf(a, a, c3); c4 = fmaf(b, b, c4); c5 = fmaf(a, b, c5);
            }
        }

        float s1 = c1, s2 = c2, s3 = c3, s4 = c4, s5 = c5;
#pragma unroll
        for (int off = 1; off < 64; off <<= 1) {
            float y1 = __shfl_up(s1, off, 64);
            float y2 = __shfl_up(s2, off, 64);
            float y3 = __shfl_up(s3, off, 64);
            float y4 = __shfl_up(s4, off, 64);
            float y5 = __shfl_up(s5, off, 64);
            if (lane >= off) { s1 += y1; s2 += y2; s3 += y3; s4 += y4; s5 += y5; }
        }

        // table init: prefix[0] = 0 for all three periods
        if (lane == 63) {
#pragma unroll
            for (int k = 0; k < 3; k++) {
#pragma unroll
                for (int q = 0; q < 5; q++) tw[(k * 70) * 5 + q] = 0.f;
            }
        }
        // boundary writes: position t' = 6*lane+i+1; write prefix to
        // tab[k][t'/P] when P | t'; t'=336 writes totals.
        if (lane < 56) {
            float r1 = s1 - c1, r2 = s2 - c2;
            float r3 = s3 - c3, r4 = s4 - c4, r5 = s5 - c5;
#pragma unroll
            for (int i = 0; i < 6; i++) {
                float a = loc[i].x, b = loc[i].y;
                r1 += a; r2 += b;
                r3 = fmaf(a, a, r3); r4 = fmaf(b, b, r4); r5 = fmaf(a, b, r5);
                int tp = 6 * lane + i + 1;
                float tpf = (float)tp;
                if (tp == TT) {
                    tw[1050] = r1; tw[1051] = r2; tw[1052] = r3;
                    tw[1053] = r4; tw[1054] = r5;
                }
#pragma unroll
                for (int k = 0; k < 3; k++) {
                    if (cfg.vp[k]) {
                        int q = (int)(tpf * cfg.rp[k] + 0.001f);
                        if (q * cfg.P[k] == tp && q <= 68) {
                            int ix = (k * 70 + q) * 5;
                            tw[ix + 0] = r1; tw[ix + 1] = r2; tw[ix + 2] = r3;
                            tw[ix + 3] = r4; tw[ix + 4] = r5;
                        }
                    }
                }
            }
        }
        // wave-private table: no __syncthreads; per-wave lgkm ordering suffices.

        ULL anyMask = 0ull;
#pragma unroll
        for (int rI = 0; rI < 4; rI++) {
            int i = lane + 64 * rI;
            int s, e;
            bool kept = slot_patch(cfg, i, s, e);
            ULL bal = __ballot(kept);
            anyMask |= bal;
            if (bal == 0ull) continue;          // wave-uniform early-out
            if (kept) {
                int k = (i >= 136) ? 2 : ((i >= 68) ? 1 : 0);
                int si = i - k * 68;
                bool tail = (si == cfg.nseg[k]);
                const float* pS = tw + (k * 70 + si) * 5;
                const float* pE = tail ? (tw + 1050) : (tw + (k * 70 + si + 1) * 5);
                float S1 = pE[0] - pS[0];
                float S2 = pE[1] - pS[1];
                float S3 = pE[2] - pS[2];
                float S4 = pE[3] - pS[3];
                float S5 = pE[4] - pS[4];
                lsum += patch_loss_f32(S1, S2, S3, S4, S5, e - s);
                lcnt += 1;
            }
        }
        if (anyMask == 0ull) {
            if (lane == 0) {
                lsum += patch_loss_f32(tw[1050], tw[1051], tw[1052],
                                       tw[1053], tw[1054], TT);
                lcnt += 1;
            }
        }
    }

    for (int off = 32; off; off >>= 1) {
        lsum += __shfl_down(lsum, off, 64);
        lcnt += __shfl_down(lcnt, off, 64);
    }
    if (lane == 0) { wls[wave] = (double)lsum; wlc[wave] = lcnt; }
    __syncthreads();
    if (tid == 0) {
        double L = 0.0, M = 0.0;
        int C = 0;
#pragma unroll
        for (int wv = 0; wv < WV; wv++) { L += wls[wv]; C += wlc[wv]; M += wms[wv]; }
        blkout[3 * lb + 0] = L;
        blkout[3 * lb + 1] = (double)C;
        blkout[3 * lb + 2] = M;
        __threadfence();
        unsigned old = atomicAdd(cnt, 1u);
        *isLast = (old == (unsigned)(NFB - 1)) ? 1 : 0;
    }
    __syncthreads();

    // ---- last block performs the final reduction (reduce3 fold-in) ----
    if (*isLast) {
        __threadfence();
        double ls = 0.0, lc2 = 0.0, ms2 = 0.0;
        for (int i = tid; i < NFB; i += 512) {
            ls += blkout[3 * i + 0];
            lc2 += blkout[3 * i + 1];
            ms2 += blkout[3 * i + 2];
        }
        for (int off = 32; off; off >>= 1) {
            ls += __shfl_down(ls, off, 64);
            lc2 += __shfl_down(lc2, off, 64);
            ms2 += __shfl_down(ms2, off, 64);
        }
        if (lane == 0) { red[wave] = ls; red[8 + wave] = lc2; red[16 + wave] = ms2; }
        __syncthreads();
        if (tid == 0) {
            double L = 0, C = 0, M = 0;
#pragma unroll
            for (int i = 0; i < 8; i++) { L += red[i]; C += red[8 + i]; M += red[16 + i]; }
            double mse = M / (double)((size_t)NB * TT * NF);
            double avg = (C > 0.0) ? (L / C) : 0.0;
            out[0] = (float)(0.5 * mse + 0.5 * avg);
        }
    }
}

// ---------------------------------------------------------------------------
// FALLBACK Kernel: transpose [B,T,F] -> float2{tg,fc}[B*F][T], fused MSE.
// ---------------------------------------------------------------------------
__global__ __launch_bounds__(256) void transpose_k(const float* __restrict__ fc,
                                                   const float* __restrict__ tg,
                                                   float2* __restrict__ out,
                                                   double* __restrict__ msep,
                                                   double* __restrict__ acc) {
    __shared__ float ta[32][33];
    __shared__ float tb[32][33];
    __shared__ double wacc[4];
    const int b = blockIdx.z;
    const int t0 = blockIdx.x * 32, f0 = blockIdx.y * 32;
    const int tx = threadIdx.x, ty = threadIdx.y;   // block (32, 8)
    const size_t base = (size_t)b * TT * NF;
    double ms = 0.0;
#pragma unroll
    for (int k = 0; k < 4; k++) {
        int t = t0 + ty + 8 * k, f = f0 + tx;
        if (t < TT && f < NF) {
            float a = tg[base + (size_t)t * NF + f];
            float c = fc[base + (size_t)t * NF + f];
            ta[ty + 8 * k][tx] = a;
            tb[ty + 8 * k][tx] = c;
            double d = (double)a - (double)c;
            ms += d * d;
        }
    }
    __syncthreads();
#pragma unroll
    for (int k = 0; k < 4; k++) {
        int f = f0 + ty + 8 * k, t = t0 + tx;
        if (t < TT && f < NF) {
            out[((size_t)b * NF + f) * TT + t] =
                make_float2(ta[tx][ty + 8 * k], tb[tx][ty + 8 * k]);
        }
    }
    for (int off = 32; off; off >>= 1) ms += __shfl_down(ms, off, 64);
    int flat = ty * 32 + tx;
    int lane = flat & 63, wid = flat >> 6;
    if (lane == 0) wacc[wid] = ms;
    __syncthreads();
    if (flat == 0) {
        double tot = wacc[0] + wacc[1] + wacc[2] + wacc[3];
        if (msep) {
            int blk = (blockIdx.z * TGY + blockIdx.y) * TGX + blockIdx.x;
            msep[blk] = tot;
        } else {
            atomicAdd(&acc[0], tot);
        }
    }
}

// ---------------------------------------------------------------------------
__global__ void mse_k(const float* __restrict__ fc, const float* __restrict__ tg,
                      double* __restrict__ acc) {
    const size_t N4 = (size_t)NB * TT * NF / 4;
    const float4* a4 = (const float4*)fc;
    const float4* b4 = (const float4*)tg;
    double s = 0.0;
    for (size_t i = (size_t)blockIdx.x * blockDim.x + threadIdx.x; i < N4;
         i += (size_t)gridDim.x * blockDim.x) {
        float4 a = a4[i], b = b4[i];
        double d0 = (double)a.x - (double)b.x;
        double d1 = (double)a.y - (double)b.y;
        double d2 = (double)a.z - (double)b.z;
        double d3 = (double)a.w - (double)b.w;
        s += d0 * d0 + d1 * d1 + d2 * d2 + d3 * d3;
    }
    for (int off = 32; off; off >>= 1) s += __shfl_down(s, off, 64);
    __shared__ double wsum[4];
    int flat = threadIdx.x;
    int lane = flat & 63, wid = flat >> 6;
    if (lane == 0) wsum[wid] = s;
    __syncthreads();
    if (flat == 0) atomicAdd(&acc[0], wsum[0] + wsum[1] + wsum[2] + wsum[3]);
}

// ---------------------------------------------------------------------------
// FALLBACK: self-contained series kernel (VALU DFT + topk + serial patches).
// ---------------------------------------------------------------------------
__device__ __forceinline__ void patch_body(const float2* tsw, int lane,
                                           int fr0, int fr1, int fr2,
                                           double& lsum, double& lcnt) {
    PatchCfg cfg;
    make_cfg(fr0, fr1, fr2, cfg);
    ULL anyMask = 0ull;
#pragma unroll
    for (int rI = 0; rI < 4; rI++) {
        int s, e;
        bool kept = slot_patch(cfg, lane + 64 * rI, s, e);
        anyMask |= __ballot(kept);
        if (kept) {
            double S1 = 0, S2 = 0, S3 = 0, S4 = 0, S5 = 0;
            for (int t = s; t < e; t++) {
                float2 v = tsw[t];
                double a = (double)v.x, b = (double)v.y;
                S1 += a; S2 += b;
                S3 += a * a; S4 += b * b; S5 += a * b;
            }
            lsum += patch_loss(S1, S2, S3, S4, S5, (double)(e - s));
            lcnt += 1.0;
        }
    }
    if (anyMask == 0ull) {
        double S1 = 0, S2 = 0, S3 = 0, S4 = 0, S5 = 0;
        for (int t = lane; t < TT; t += 64) {
            float2 v = tsw[t];
            double a = (double)v.x, b = (double)v.y;
            S1 += a; S2 += b;
            S3 += a * a; S4 += b * b; S5 += a * b;
        }
        for (int off = 32; off; off >>= 1) {
            S1 += __shfl_down(S1, off, 64);
            S2 += __shfl_down(S2, off, 64);
            S3 += __shfl_down(S3, off, 64);
            S4 += __shfl_down(S4, off, 64);
            S5 += __shfl_down(S5, off, 64);
        }
        if (lane == 0) {
            lsum += patch_loss(S1, S2, S3, S4, S5, (double)TT);
            lcnt += 1.0;
        }
    }
}

__global__ __launch_bounds__(256, 6) void series_k(const float2* __restrict__ tsG,
                                                   const float* __restrict__ fcG,
                                                   const float* __restrict__ tgG,
                                                   int transposed,
                                                   double2* __restrict__ pairs,
                                                   double* __restrict__ acc) {
    const int w = threadIdx.x >> 6, lane = threadIdx.x & 63;
    const int ser = blockIdx.x * WPB + w;
    __shared__ float2 ts[WPB][TT];
    __shared__ float4 zb[WPB][84];

    if (transposed) {
        const float2* sp = tsG + (size_t)ser * TT;
        for (int t = lane; t < TT; t += 64) ts[w][t] = sp[t];
    } else {
        int b = ser / NF, f = ser - b * NF;
        const float* tp = tgG + (size_t)b * TT * NF + f;
        const float* fp = fcG + (size_t)b * TT * NF + f;
        for (int t = lane; t < TT; t += 64)
            ts[w][t] = make_float2(tp[(size_t)t * NF], fp[(size_t)t * NF]);
    }
    __syncthreads();

    for (int t = lane; t < 84; t += 64) {
        float x0 = ts[w][t].x, x1 = ts[w][t + 84].x;
        float x2 = ts[w][t + 168].x, x3 = ts[w][t + 252].x;
        float a = x0 + x2, b2 = x1 + x3, c = x0 - x2, d = x1 - x3;
        zb[w][t] = make_float4(a + b2, a - b2, c, d);
    }
    __syncthreads();

    const double TWOPI = 6.283185307179586476925286766559;
    int fb[3] = {1 + lane, 65 + lane, 129 + lane};
    float cc[3], sn[3], re[3], im[3], cd[3], sd[3], sgn[3];
    int selA[3];
#pragma unroll
    for (int q = 0; q < 3; q++) {
        int f = fb[q], cls = f & 3;
        double dl = (double)f * (TWOPI / 336.0);
        cd[q] = (float)cos(dl);
        sd[q] = (float)sin(dl);
        cc[q] = 1.0f; sn[q] = 0.0f; re[q] = 0.0f; im[q] = 0.0f;
        sgn[q] = (cls == 1) ? -1.0f : ((cls == 3) ? 1.0f : 0.0f);
        selA[q] = (cls == 0) ? 0 : ((cls == 2) ? 1 : 2);
    }
    for (int t = 0; t < 84; t++) {
        float4 zv = zb[w][t];
#pragma unroll
        for (int q = 0; q < 3; q++) {
            float zr = (selA[q] == 0) ? zv.x : ((selA[q] == 1) ? zv.y : zv.z);
            float zi = sgn[q] * zv.w;
            re[q] = fmaf(zr, cc[q], re[q]);
            re[q] = fmaf(zi, sn[q], re[q]);
            im[q] = fmaf(zi, cc[q], im[q]);
            im[q] = fmaf(-zr, sn[q], im[q]);
            float nc = fmaf(cc[q], cd[q], -(sn[q] * sd[q]));
            float ns = fmaf(sn[q], cd[q], cc[q] * sd[q]);
            cc[q] = nc; sn[q] = ns;
        }
    }

    ULL k0 = 0, k1 = 0, k2 = 0;
#pragma unroll
    for (int q = 0; q < 3; q++) {
        float a2 = fmaf(re[q], re[q], im[q] * im[q]);
        ULL key = ((ULL)__float_as_uint(a2) << 32) |
                  (ULL)(0xFFFFFFFFu - (unsigned)fb[q]);
        if (fb[q] > 168) key = 0ull;
        ins3(k0, k1, k2, key);
    }
    for (int m = 1; m < 64; m <<= 1) {
        ULL b0 = __shfl_xor(k0, m, 64);
        ULL b1 = __shfl_xor(k1, m, 64);
        ULL b2 = __shfl_xor(k2, m, 64);
        ins3(k0, k1, k2, b0); ins3(k0, k1, k2, b1); ins3(k0, k1, k2, b2);
    }

    int fr0 = (int)(0xFFFFFFFFu - (unsigned)(k0 & 0xFFFFFFFFull));
    int fr1 = (int)(0xFFFFFFFFu - (unsigned)(k1 & 0xFFFFFFFFull));
    int fr2 = (int)(0xFFFFFFFFu - (unsigned)(k2 & 0xFFFFFFFFull));

    double lsum = 0.0, lcnt = 0.0;
    patch_body(&ts[w][0], lane, fr0, fr1, fr2, lsum, lcnt);

    for (int off = 32; off; off >>= 1) {
        lsum += __shfl_down(lsum, off, 64);
        lcnt += __shfl_down(lcnt, off, 64);
    }
    if (lane == 0) {
        if (pairs) {
            pairs[ser] = make_double2(lsum, lcnt);
        } else {
            atomicAdd(&acc[1], lsum);
            atomicAdd(&acc[2], lcnt);
        }
    }
}

// fallback reduce over pairs+msep (round-3 style)
__global__ __launch_bounds__(1024) void reduce_k(const double2* __restrict__ pairs,
                                                 const double* __restrict__ msep,
                                                 int nmse,
                                                 float* __restrict__ out) {
    const int tid = threadIdx.x;
    double ls = 0.0, lc = 0.0, ms = 0.0;
    for (int i = tid; i < NSER; i += 1024) {
        double2 p = pairs[i];
        ls += p.x; lc += p.y;
    }
    for (int i = tid; i < nmse; i += 1024) ms += msep[i];
    for (int off = 32; off; off >>= 1) {
        ls += __shfl_down(ls, off, 64);
        lc += __shfl_down(lc, off, 64);
        ms += __shfl_down(ms, off, 64);
    }
    __shared__ double sl[16], sc[16], sm[16];
    int lane = tid & 63, wid = tid >> 6;
    if (lane == 0) { sl[wid] = ls; sc[wid] = lc; sm[wid] = ms; }
    __syncthreads();
    if (tid == 0) {
        double L = 0, C = 0, M = 0;
        for (int i = 0; i < 16; i++) { L += sl[i]; C += sc[i]; M += sm[i]; }
        double mse = M / (double)((size_t)NB * TT * NF);
        double avg = (C > 0.0) ? (L / C) : 0.0;
        out[0] = (float)(0.5 * mse + 0.5 * avg);
    }
}

__global__ void finalize_k(const double* __restrict__ acc, float* __restrict__ out) {
    double mse = acc[0] / (double)((size_t)NB * TT * NF);
    double avg = (acc[2] > 0.0) ? (acc[1] / acc[2]) : 0.0;
    out[0] = (float)(0.5 * mse + 0.5 * avg);
}

// ---------------------------------------------------------------------------
extern "C" void kernel_launch(void* const* d_in, const int* in_sizes, int n_in,
                              void* d_out, int out_size, void* d_ws, size_t ws_size,
                              hipStream_t stream) {
    const float* fc = (const float*)d_in[0];   // forecast
    const float* tg = (const float*)d_in[1];   // target
    float* out = (float*)d_out;
    char* ws = (char*)d_ws;
    double* acc = (double*)ws;
    unsigned* cnt = (unsigned*)(ws + 32);      // big2: block-completion counter

    // layout: [0,64) acc/cnt | msep | blkout/pairs | (unused topk) | Wb | (fb tsT)
    const size_t OFF_MSE = 64;
    const size_t OFF_PAIR = OFF_MSE + (size_t)NMSEP * sizeof(double);        // 62016
    const size_t OFF_TOP = OFF_PAIR + (size_t)NSER * sizeof(double2);        // 390720
    const size_t OFF_W = OFF_TOP + (size_t)NSER * sizeof(uint4);             // 719424
    const size_t OFF_END2 = OFF_W + (size_t)TT * KP * sizeof(unsigned short);// 955968
    const size_t bytesT = (size_t)NSER * TT * sizeof(float2);
    const bool big2 = (ws_size >= OFF_END2);                   // main path
    const size_t R3_OFF_TS = OFF_PAIR + (size_t)NSER * sizeof(double2);
    const bool big = !big2 && (ws_size >= R3_OFF_TS + bytesT);
    const bool mid = !big2 && !big && (ws_size >= OFF_MSE + bytesT);

    double* msep = (double*)(ws + OFF_MSE);
    double* blkout = (double*)(ws + OFF_PAIR);   // 3*NFB doubles (31 KB)
    unsigned short* Wb = (unsigned short*)(ws + OFF_W);

    dim3 tg_grid(TGX, TGY, NB);
    dim3 tg_blk(32, 8);

    if (big2) {
        hipMemsetAsync(d_ws, 0, 64, stream);     // zero acc + counter
        twiddle_k<<<TT, 128, 0, stream>>>(Wb);
        fused_k<<<NFBG, 64 * WV, 0, stream>>>(tg, fc, Wb, blkout, cnt, out);
    } else if (big) {
        float2* tsT = (float2*)(ws + R3_OFF_TS);
        transpose_k<<<tg_grid, tg_blk, 0, stream>>>(fc, tg, tsT, msep, acc);
        series_k<<<NSER / WPB, 64 * WPB, 0, stream>>>(tsT, fc, tg, 1,
                                                      (double2*)blkout, acc);
        reduce_k<<<1, 1024, 0, stream>>>((double2*)blkout, msep, NMSEP, out);
    } else if (mid) {
        float2* tsT = (float2*)(ws + OFF_MSE);
        hipMemsetAsync(d_ws, 0, 64, stream);
        transpose_k<<<tg_grid, tg_blk, 0, stream>>>(fc, tg, tsT, nullptr, acc);
        series_k<<<NSER / WPB, 64 * WPB, 0, stream>>>(tsT, fc, tg, 1, nullptr, acc);
        finalize_k<<<1, 1, 0, stream>>>(acc, out);
    } else {
        hipMemsetAsync(d_ws, 0, 64, stream);
        mse_k<<<1024, 256, 0, stream>>>(fc, tg, acc);
        series_k<<<NSER / WPB, 64 * WPB, 0, stream>>>(nullptr, fc, tg, 0, nullptr, acc);
        finalize_k<<<1, 1, 0, stream>>>(acc, out);
    }
}

// Round 8
// 152.105 us; speedup vs baseline: 1.8613x; 1.3203x over previous
//
#include <hip/hip_runtime.h>
#include <hip/hip_bf16.h>

#define TT 336
#define NF 321
#define NB 64
#define NSER (NB * NF)   // 20544 series
#define WPB 4            // waves (series) per block in FALLBACK series kernel
#define KP 352           // K padded to multiple of 32 for 16x16x32 MFMA
#define LDA 360          // LDS row stride (ushorts) for bf16 A tile
#define SPP 16           // series per fused block (64B line = 16 floats)
#define WV 8             // waves per fused block (512 threads)
#define NFB (NSER / SPP)     // 1284 fused blocks
#define NFBG 1288            // dispatched (8 x 161, guard skips 4)
#define TSP 340          // ts row stride in float2 (2720B, 16B aligned)

// per-wave boundary tables: [3 periods][70 slots][5 stats] + totals[5] + pad
#define TWS 1056         // floats per wave (4224 B)

// transpose grid (fallback paths): 11 x 11 x 64 blocks
#define TGX 11
#define TGY 11
#define NMSEP (TGX * TGY * NB)   // 7744 per-block MSE partials (fallback)

typedef __attribute__((ext_vector_type(8))) short bf16x8;
typedef __attribute__((ext_vector_type(4))) float f32x4;
typedef unsigned long long ULL;

__device__ __forceinline__ unsigned short f2bf(float v) {
    unsigned x = __float_as_uint(v);
    x += 0x7FFFu + ((x >> 16) & 1u);   // RNE; inputs are finite
    return (unsigned short)(x >> 16);
}

// sorted-3 insert (a0 >= a1 >= a2)
__device__ __forceinline__ void ins3(ULL& a0, ULL& a1, ULL& a2, ULL x) {
    ULL hi = a0 > x ? a0 : x;
    ULL lo = a0 > x ? x : a0;
    a0 = hi;
    ULL hi1 = a1 > lo ? a1 : lo;
    ULL lo1 = a1 > lo ? lo : a1;
    a1 = hi1;
    a2 = a2 > lo1 ? a2 : lo1;
}

// exact integer 336/d via fast fp32 division (error ~1e-7 rel, 100x margin
// to the 1/336 distance from integer boundaries). d>336 (garbage) -> 0.
__device__ __forceinline__ int idiv336(int d) {
    return (int)(__fdividef(336.0f, (float)d));
}

// ---------------------------------------------------------------------------
// Twiddle matrix: Wb[n][k], n=2(f-1) -> cos(2pi f k/336), n=2(f-1)+1 -> sin.
// ---------------------------------------------------------------------------
__global__ void twiddle_k(unsigned short* __restrict__ Wb) {
    int n = blockIdx.x;          // 0..335
    int f = (n >> 1) + 1;
    int isSin = n & 1;
    for (int k = threadIdx.x; k < KP; k += blockDim.x) {
        float v = 0.0f;
        if (k < TT) {
            int r = (f * k) % TT;
            float ang = 6.2831853071795864769f * (float)r / 336.0f;
            v = isSin ? sinf(ang) : cosf(ang);
        }
        Wb[(size_t)n * KP + k] = f2bf(v);
    }
}

// ---------------------------------------------------------------------------
// All-fp32 patch loss (r16: matches the fp32 JAX reference; absmax 0.0625,
// deterministic, inside tolerance).
// ---------------------------------------------------------------------------
__device__ __forceinline__ float patch_loss_f32(float S1, float S2, float S3,
                                                float S4, float S5, int n) {
    float nnf = (float)n;
    float invf = 1.0f / nnf;
    float tvs = S3 - S1 * S1 * invf; tvs = tvs > 0.f ? tvs : 0.f;
    float fvs = S4 - S2 * S2 * invf; fvs = fvs > 0.f ? fvs : 0.f;
    float num = S5 - S1 * S2 * invf;
    float corr = num / (sqrtf(tvs * fvs) + 1e-8f);
    float closs = 1.0f - fabsf(corr);
    float vloss = fabsf(tvs - fvs) / (tvs + (nnf - 1.0f) * 1e-8f);
    float mloss = fabsf(S1 - S2) / (fabsf(S1) + nnf * 1e-8f);
    return closs + vloss + mloss;
}

// full-fp64 patch loss (fallback series kernel only)
__device__ __forceinline__ double patch_loss(double S1, double S2, double S3,
                                             double S4, double S5, double nn) {
    double mt = S1 / nn, mf = S2 / nn;
    double tvs = S3 - nn * mt * mt; tvs = tvs > 0.0 ? tvs : 0.0;
    double fvs = S4 - nn * mf * mf; fvs = fvs > 0.0 ? fvs : 0.0;
    double num = S5 - nn * mt * mf;
    double corr = num / (sqrt(tvs * fvs) + 1e-8);
    double closs = 1.0 - fabs(corr);
    double tvar = tvs / (nn - 1.0), fvar = fvs / (nn - 1.0);
    double vloss = fabs(tvar - fvar) / (tvar + 1e-8);
    double mloss = fabs(mt - mf) / (fabs(mt) + 1e-8);
    return closs + vloss + mloss;
}

// ---------------------------------------------------------------------------
struct PatchCfg {
    int P[3], nseg[3], rs[3];
    float rp[3];          // 1/P for exact boundary division (fused path)
    bool vp[3], hr[3];
};

__device__ __forceinline__ void make_cfg(int fr0, int fr1, int fr2, PatchCfg& c) {
    c.P[0] = idiv336(fr0); c.P[1] = idiv336(fr1); c.P[2] = idiv336(fr2);
    c.vp[0] = (c.P[0] >= 5);
    c.vp[1] = (c.P[1] >= 5) && (c.P[1] != c.P[0]);
    c.vp[2] = (c.P[2] >= 5) && (c.P[2] != c.P[0]) && (c.P[2] != c.P[1]);
#pragma unroll
    for (int q = 0; q < 3; q++) {
        c.nseg[q] = idiv336(c.P[q] > 0 ? c.P[q] : 1);
        c.rs[q] = c.nseg[q] * c.P[q];
        c.hr[q] = c.vp[q] && ((TT - c.rs[q]) >= 5);
        c.rp[q] = (c.P[q] > 0) ? __frcp_rn((float)c.P[q]) : 0.0f;
    }
}

// slot i in [0,204) -> (s,e,kept) with dedup against earlier periods
__device__ __forceinline__ bool slot_patch(const PatchCfg& c, int i, int& s, int& e) {
    bool kept = false;
    s = 0; e = 0;
    if (i < 204) {
        int k = (i >= 136) ? 2 : ((i >= 68) ? 1 : 0);
        int si = i - k * 68;
        if (c.vp[k]) {
            if (si < c.nseg[k]) { s = c.P[k] * si; e = s + c.P[k]; kept = true; }
            else if (si == c.nseg[k] && c.hr[k]) { s = c.rs[k]; e = TT; kept = true; }
            if (kept) {
#pragma unroll
                for (int j = 0; j < 2; j++) {
                    if (j < k && c.vp[j]) {
                        bool dup = (s == c.rs[j]) && (e == TT) && c.hr[j];
                        int len = e - s;
                        if (len == c.P[j] && s < c.rs[j] && (s % c.P[j]) == 0) dup = true;
                        if (dup) kept = false;
                    }
                }
            }
        }
    }
    return kept;
}

// ---------------------------------------------------------------------------
// Round-23 FUSED kernel: exact r20 (78us verified) body EXCEPT the ts/MSE
// writes are DEFERRED past phase P. r21/r22's restructure (ts-overlay tables,
// masked-tail MFMA, LDS squeeze to 3 blocks/CU, reduce fold-in) added ~60us
// of pure stall at unchanged occupancy — fully reverted.
// Reorder rationale: phase P consumes ONLY sA (tg); ts isn't read until
// phase T (already behind 2 more barriers). Writing ts + MSE after phase P
// hides the fc-load latency and 43KB of LDS writes under the MFMA/top-3
// compute instead of the phase-L barrier. va/vc stay live through P
// (+22 VGPR, harmless: occupancy is LDS-bound at 2 blocks/CU).
// ---------------------------------------------------------------------------
__global__ __launch_bounds__(512) void fused_k(const float* __restrict__ tgO,
                                               const float* __restrict__ fcO,
                                               const unsigned short* __restrict__ Wb,
                                               double* __restrict__ blkout) {
    // region A [0,43520): ts float2[SPP][TSP]
    // region B [43520,77312):
    //   phase P: sA ushort[SPP][LDA] (11520) + tk3 ULL[WV][16][3] (3072)
    //   phase T: per-wave boundary tables float[WV][TWS] (33792)
    __shared__ __align__(16) char smem[43520 + WV * TWS * 4];
    float2* ts = (float2*)smem;
    unsigned short* sA = (unsigned short*)(smem + 43520);
    ULL* tk3 = (ULL*)(smem + 43520 + 11520);
    float* tabAll = (float*)(smem + 43520);
    __shared__ uint4 tkf[SPP];
    __shared__ double wms[WV], wls[WV];
    __shared__ int wlc[WV];

    const int tid = threadIdx.x;
    const int wave = tid >> 6, lane = tid & 63;
    const int lb = (blockIdx.x & 7) * 161 + (blockIdx.x >> 3);
    if (lb >= NFB) return;
    const int serBase = lb * SPP;

    // ---- phase L (part 1): load + sA(bf16 of tg) only; ts/MSE deferred ----
    const int j = tid & 15, tch = tid >> 4;   // 32 t-chunks (16x11 + 16x10)
    int t0, nT;
    if (tch < 16) { t0 = tch * 11; nT = 11; }
    else          { t0 = 176 + (tch - 16) * 10; nT = 10; }
    float va[11], vc[11];
    {
        const int ser = serBase + j;
        const int bb = ser / NF, ff = ser - bb * NF;
        const float* tb_ = tgO + (size_t)bb * TT * NF + ff;
        const float* fb_ = fcO + (size_t)bb * TT * NF + ff;
#pragma unroll
        for (int i = 0; i < 11; i++) if (i < nT) va[i] = tb_[(size_t)(t0 + i) * NF];
#pragma unroll
        for (int i = 0; i < 11; i++) if (i < nT) vc[i] = fb_[(size_t)(t0 + i) * NF];
#pragma unroll
        for (int i = 0; i < 11; i++) {
            if (i < nT) sA[j * LDA + (t0 + i)] = f2bf(va[i]);
        }
        if (tid < SPP * 16) sA[(tid & 15) * LDA + TT + (tid >> 4)] = 0;  // K pad
    }
    __syncthreads();   // sA ready; fc loads may still be in flight

    // ---- phase P: PSD + top-3 via MFMA ----
    const int quad = lane >> 4, c = lane & 15;
    ULL t0k[4] = {0, 0, 0, 0}, t1k[4] = {0, 0, 0, 0}, t2k[4] = {0, 0, 0, 0};
    {
        const unsigned short* aRow = sA + c * LDA + quad * 8;
        // 21 nt tiles over 8 waves: waves 0-4 get 3, waves 5-7 get 2
        const int ntStart = (wave < 5) ? wave * 3 : 15 + (wave - 5) * 2;
        const int ntEnd = ntStart + ((wave < 5) ? 3 : 2);

        for (int nt = ntStart; nt < ntEnd; nt++) {
            const unsigned short* bRow = Wb + (size_t)(nt * 16 + c) * KP + quad * 8;
            f32x4 acc = (f32x4){0.f, 0.f, 0.f, 0.f};
#pragma unroll
            for (int ks = 0; ks < 11; ks++) {
                bf16x8 a = *(const bf16x8*)(aRow + ks * 32);
                bf16x8 b = *(const bf16x8*)(bRow + ks * 32);
                acc = __builtin_amdgcn_mfma_f32_16x16x32_bf16(a, b, acc, 0, 0, 0);
            }
            int n = nt * 16 + c;
            unsigned fidx = (unsigned)((n >> 1) + 1);
            unsigned ftag = 0xFFFFFFFFu - fidx;
            bool odd = (n & 1) != 0;
#pragma unroll
            for (int r = 0; r < 4; r++) {
                float v = acc[r];
                float p = v * v;
                p += __shfl_xor(p, 1, 64);            // pair cos/sin columns
                ULL key = odd ? 0ull
                              : (((ULL)__float_as_uint(p) << 32) | (ULL)ftag);
                ins3(t0k[r], t1k[r], t2k[r], key);
            }
        }
#pragma unroll
        for (int m = 2; m <= 8; m <<= 1) {
#pragma unroll
            for (int r = 0; r < 4; r++) {
                ULL b0 = __shfl_xor(t0k[r], m, 64);
                ULL b1 = __shfl_xor(t1k[r], m, 64);
                ULL b2 = __shfl_xor(t2k[r], m, 64);
                ins3(t0k[r], t1k[r], t2k[r], b0);
                ins3(t0k[r], t1k[r], t2k[r], b1);
                ins3(t0k[r], t1k[r], t2k[r], b2);
            }
        }
    }

    // ---- phase L (part 2, deferred): ts writes + fused MSE ----
    // fc-load latency was hidden under phase P; ts isn't read until after
    // the next two barriers, so the tk3 barrier below covers these writes.
    {
        float ms = 0.0f;
#pragma unroll
        for (int i = 0; i < 11; i++) {
            if (i < nT) {
                int t = t0 + i;
                ts[j * TSP + t] = make_float2(va[i], vc[i]);
                float d = va[i] - vc[i];
                ms = fmaf(d, d, ms);
            }
        }
        for (int off = 32; off; off >>= 1) ms += __shfl_down(ms, off, 64);
        if (lane == 0) wms[wave] = (double)ms;
    }

    if (c == 0) {
#pragma unroll
        for (int r = 0; r < 4; r++) {
            int s = quad * 4 + r;
            tk3[(wave * 16 + s) * 3 + 0] = t0k[r];
            tk3[(wave * 16 + s) * 3 + 1] = t1k[r];
            tk3[(wave * 16 + s) * 3 + 2] = t2k[r];
        }
    }
    __syncthreads();
    if (tid < SPP) {
        ULL k0 = 0, k1 = 0, k2 = 0;
#pragma unroll
        for (int wv = 0; wv < WV; wv++) {
#pragma unroll
            for (int jj = 0; jj < 3; jj++) ins3(k0, k1, k2, tk3[(wv * 16 + tid) * 3 + jj]);
        }
        unsigned f0 = 0xFFFFFFFFu - (unsigned)(k0 & 0xFFFFFFFFull);
        unsigned f1 = 0xFFFFFFFFu - (unsigned)(k1 & 0xFFFFFFFFull);
        unsigned f2 = 0xFFFFFFFFu - (unsigned)(k2 & 0xFFFFFFFFull);
        tkf[tid] = make_uint4(f0, f1, f2, 0u);
    }
    __syncthreads();   // tk3/sA dead; boundary tables may overlay them

    // ---- phase T: 2 serial series per wave, boundary tables (wave-private) --
    float* tw = tabAll + wave * TWS;   // [3][70][5] + totals at [1050..1054]
    float lsum = 0.0f;
    int lcnt = 0;
#pragma unroll 1
    for (int r = 0; r < 2; r++) {
        const int jj = (wave << 1) | r;

        uint4 tk = tkf[jj];
        PatchCfg cfg;
        make_cfg((int)tk.x, (int)tk.y, (int)tk.z, cfg);

        float2 loc[6];
        float c1 = 0.f, c2 = 0.f, c3 = 0.f, c4 = 0.f, c5 = 0.f;
        if (lane < 56) {
            const float4* lp = (const float4*)(ts + jj * TSP + 6 * lane);  // 48B
            float4 fa = lp[0], fb = lp[1], fcc = lp[2];
            loc[0] = make_float2(fa.x, fa.y); loc[1] = make_float2(fa.z, fa.w);
            loc[2] = make_float2(fb.x, fb.y); loc[3] = make_float2(fb.z, fb.w);
            loc[4] = make_float2(fcc.x, fcc.y); loc[5] = make_float2(fcc.z, fcc.w);
#pragma unroll
            for (int i = 0; i < 6; i++) {
                float a = loc[i].x, b = loc[i].y;
                c1 += a; c2 += b;
                c3 = fmaf(a, a, c3); c4 = fmaf(b, b, c4); c5 = fmaf(a, b, c5);
            }
        }

        float s1 = c1, s2 = c2, s3 = c3, s4 = c4, s5 = c5;
#pragma unroll
        for (int off = 1; off < 64; off <<= 1) {
            float y1 = __shfl_up(s1, off, 64);
            float y2 = __shfl_up(s2, off, 64);
            float y3 = __shfl_up(s3, off, 64);
            float y4 = __shfl_up(s4, off, 64);
            float y5 = __shfl_up(s5, off, 64);
            if (lane >= off) { s1 += y1; s2 += y2; s3 += y3; s4 += y4; s5 += y5; }
        }

        // table init: prefix[0] = 0 for all three periods
        if (lane == 63) {
#pragma unroll
            for (int k = 0; k < 3; k++) {
#pragma unroll
                for (int q = 0; q < 5; q++) tw[(k * 70) * 5 + q] = 0.f;
            }
        }
        // boundary writes: position t' = 6*lane+i+1; write prefix to
        // tab[k][t'/P] when P | t'; t'=336 writes totals.
        if (lane < 56) {
            float r1 = s1 - c1, r2 = s2 - c2;
            float r3 = s3 - c3, r4 = s4 - c4, r5 = s5 - c5;
#pragma unroll
            for (int i = 0; i < 6; i++) {
                float a = loc[i].x, b = loc[i].y;
                r1 += a; r2 += b;
                r3 = fmaf(a, a, r3); r4 = fmaf(b, b, r4); r5 = fmaf(a, b, r5);
                int tp = 6 * lane + i + 1;
                float tpf = (float)tp;
                if (tp == TT) {
                    tw[1050] = r1; tw[1051] = r2; tw[1052] = r3;
                    tw[1053] = r4; tw[1054] = r5;
                }
#pragma unroll
                for (int k = 0; k < 3; k++) {
                    if (cfg.vp[k]) {
                        int q = (int)(tpf * cfg.rp[k] + 0.001f);
                        if (q * cfg.P[k] == tp && q <= 68) {
                            int ix = (k * 70 + q) * 5;
                            tw[ix + 0] = r1; tw[ix + 1] = r2; tw[ix + 2] = r3;
                            tw[ix + 3] = r4; tw[ix + 4] = r5;
                        }
                    }
                }
            }
        }
        // wave-private table: no __syncthreads; per-wave lgkm ordering suffices.

        ULL anyMask = 0ull;
#pragma unroll
        for (int rI = 0; rI < 4; rI++) {
            int i = lane + 64 * rI;
            int s, e;
            bool kept = slot_patch(cfg, i, s, e);
            ULL bal = __ballot(kept);
            anyMask |= bal;
            if (bal == 0ull) continue;          // wave-uniform early-out
            if (kept) {
                int k = (i >= 136) ? 2 : ((i >= 68) ? 1 : 0);
                int si = i - k * 68;
                bool tail = (si == cfg.nseg[k]);
                const float* pS = tw + (k * 70 + si) * 5;
                const float* pE = tail ? (tw + 1050) : (tw + (k * 70 + si + 1) * 5);
                float S1 = pE[0] - pS[0];
                float S2 = pE[1] - pS[1];
                float S3 = pE[2] - pS[2];
                float S4 = pE[3] - pS[3];
                float S5 = pE[4] - pS[4];
                lsum += patch_loss_f32(S1, S2, S3, S4, S5, e - s);
                lcnt += 1;
            }
        }
        if (anyMask == 0ull) {
            if (lane == 0) {
                lsum += patch_loss_f32(tw[1050], tw[1051], tw[1052],
                                       tw[1053], tw[1054], TT);
                lcnt += 1;
            }
        }
    }

    for (int off = 32; off; off >>= 1) {
        lsum += __shfl_down(lsum, off, 64);
        lcnt += __shfl_down(lcnt, off, 64);
    }
    if (lane == 0) { wls[wave] = (double)lsum; wlc[wave] = lcnt; }
    __syncthreads();
    if (tid == 0) {
        double L = 0.0, M = 0.0;
        int C = 0;
#pragma unroll
        for (int wv = 0; wv < WV; wv++) { L += wls[wv]; C += wlc[wv]; M += wms[wv]; }
        blkout[3 * lb + 0] = L;
        blkout[3 * lb + 1] = (double)C;
        blkout[3 * lb + 2] = M;
    }
}

// ---------------------------------------------------------------------------
// FALLBACK Kernel: transpose [B,T,F] -> float2{tg,fc}[B*F][T], fused MSE.
// ---------------------------------------------------------------------------
__global__ __launch_bounds__(256) void transpose_k(const float* __restrict__ fc,
                                                   const float* __restrict__ tg,
                                                   float2* __restrict__ out,
                                                   double* __restrict__ msep,
                                                   double* __restrict__ acc) {
    __shared__ float ta[32][33];
    __shared__ float tb[32][33];
    __shared__ double wacc[4];
    const int b = blockIdx.z;
    const int t0 = blockIdx.x * 32, f0 = blockIdx.y * 32;
    const int tx = threadIdx.x, ty = threadIdx.y;   // block (32, 8)
    const size_t base = (size_t)b * TT * NF;
    double ms = 0.0;
#pragma unroll
    for (int k = 0; k < 4; k++) {
        int t = t0 + ty + 8 * k, f = f0 + tx;
        if (t < TT && f < NF) {
            float a = tg[base + (size_t)t * NF + f];
            float c = fc[base + (size_t)t * NF + f];
            ta[ty + 8 * k][tx] = a;
            tb[ty + 8 * k][tx] = c;
            double d = (double)a - (double)c;
            ms += d * d;
        }
    }
    __syncthreads();
#pragma unroll
    for (int k = 0; k < 4; k++) {
        int f = f0 + ty + 8 * k, t = t0 + tx;
        if (t < TT && f < NF) {
            out[((size_t)b * NF + f) * TT + t] =
                make_float2(ta[tx][ty + 8 * k], tb[tx][ty + 8 * k]);
        }
    }
    for (int off = 32; off; off >>= 1) ms += __shfl_down(ms, off, 64);
    int flat = ty * 32 + tx;
    int lane = flat & 63, wid = flat >> 6;
    if (lane == 0) wacc[wid] = ms;
    __syncthreads();
    if (flat == 0) {
        double tot = wacc[0] + wacc[1] + wacc[2] + wacc[3];
        if (msep) {
            int blk = (blockIdx.z * TGY + blockIdx.y) * TGX + blockIdx.x;
            msep[blk] = tot;
        } else {
            atomicAdd(&acc[0], tot);
        }
    }
}

// ---------------------------------------------------------------------------
__global__ void mse_k(const float* __restrict__ fc, const float* __restrict__ tg,
                      double* __restrict__ acc) {
    const size_t N4 = (size_t)NB * TT * NF / 4;
    const float4* a4 = (const float4*)fc;
    const float4* b4 = (const float4*)tg;
    double s = 0.0;
    for (size_t i = (size_t)blockIdx.x * blockDim.x + threadIdx.x; i < N4;
         i += (size_t)gridDim.x * blockDim.x) {
        float4 a = a4[i], b = b4[i];
        double d0 = (double)a.x - (double)b.x;
        double d1 = (double)a.y - (double)b.y;
        double d2 = (double)a.z - (double)b.z;
        double d3 = (double)a.w - (double)b.w;
        s += d0 * d0 + d1 * d1 + d2 * d2 + d3 * d3;
    }
    for (int off = 32; off; off >>= 1) s += __shfl_down(s, off, 64);
    __shared__ double wsum[4];
    int flat = threadIdx.x;
    int lane = flat & 63, wid = flat >> 6;
    if (lane == 0) wsum[wid] = s;
    __syncthreads();
    if (flat == 0) atomicAdd(&acc[0], wsum[0] + wsum[1] + wsum[2] + wsum[3]);
}

// ---------------------------------------------------------------------------
// FALLBACK: self-contained series kernel (VALU DFT + topk + serial patches).
// ---------------------------------------------------------------------------
__device__ __forceinline__ void patch_body(const float2* tsw, int lane,
                                           int fr0, int fr1, int fr2,
                                           double& lsum, double& lcnt) {
    PatchCfg cfg;
    make_cfg(fr0, fr1, fr2, cfg);
    ULL anyMask = 0ull;
#pragma unroll
    for (int rI = 0; rI < 4; rI++) {
        int s, e;
        bool kept = slot_patch(cfg, lane + 64 * rI, s, e);
        anyMask |= __ballot(kept);
        if (kept) {
            double S1 = 0, S2 = 0, S3 = 0, S4 = 0, S5 = 0;
            for (int t = s; t < e; t++) {
                float2 v = tsw[t];
                double a = (double)v.x, b = (double)v.y;
                S1 += a; S2 += b;
                S3 += a * a; S4 += b * b; S5 += a * b;
            }
            lsum += patch_loss(S1, S2, S3, S4, S5, (double)(e - s));
            lcnt += 1.0;
        }
    }
    if (anyMask == 0ull) {
        double S1 = 0, S2 = 0, S3 = 0, S4 = 0, S5 = 0;
        for (int t = lane; t < TT; t += 64) {
            float2 v = tsw[t];
            double a = (double)v.x, b = (double)v.y;
            S1 += a; S2 += b;
            S3 += a * a; S4 += b * b; S5 += a * b;
        }
        for (int off = 32; off; off >>= 1) {
            S1 += __shfl_down(S1, off, 64);
            S2 += __shfl_down(S2, off, 64);
            S3 += __shfl_down(S3, off, 64);
            S4 += __shfl_down(S4, off, 64);
            S5 += __shfl_down(S5, off, 64);
        }
        if (lane == 0) {
            lsum += patch_loss(S1, S2, S3, S4, S5, (double)TT);
            lcnt += 1.0;
        }
    }
}

__global__ __launch_bounds__(256, 6) void series_k(const float2* __restrict__ tsG,
                                                   const float* __restrict__ fcG,
                                                   const float* __restrict__ tgG,
                                                   int transposed,
                                                   double2* __restrict__ pairs,
                                                   double* __restrict__ acc) {
    const int w = threadIdx.x >> 6, lane = threadIdx.x & 63;
    const int ser = blockIdx.x * WPB + w;
    __shared__ float2 ts[WPB][TT];
    __shared__ float4 zb[WPB][84];

    if (transposed) {
        const float2* sp = tsG + (size_t)ser * TT;
        for (int t = lane; t < TT; t += 64) ts[w][t] = sp[t];
    } else {
        int b = ser / NF, f = ser - b * NF;
        const float* tp = tgG + (size_t)b * TT * NF + f;
        const float* fp = fcG + (size_t)b * TT * NF + f;
        for (int t = lane; t < TT; t += 64)
            ts[w][t] = make_float2(tp[(size_t)t * NF], fp[(size_t)t * NF]);
    }
    __syncthreads();

    for (int t = lane; t < 84; t += 64) {
        float x0 = ts[w][t].x, x1 = ts[w][t + 84].x;
        float x2 = ts[w][t + 168].x, x3 = ts[w][t + 252].x;
        float a = x0 + x2, b2 = x1 + x3, c = x0 - x2, d = x1 - x3;
        zb[w][t] = make_float4(a + b2, a - b2, c, d);
    }
    __syncthreads();

    const double TWOPI = 6.283185307179586476925286766559;
    int fb[3] = {1 + lane, 65 + lane, 129 + lane};
    float cc[3], sn[3], re[3], im[3], cd[3], sd[3], sgn[3];
    int selA[3];
#pragma unroll
    for (int q = 0; q < 3; q++) {
        int f = fb[q], cls = f & 3;
        double dl = (double)f * (TWOPI / 336.0);
        cd[q] = (float)cos(dl);
        sd[q] = (float)sin(dl);
        cc[q] = 1.0f; sn[q] = 0.0f; re[q] = 0.0f; im[q] = 0.0f;
        sgn[q] = (cls == 1) ? -1.0f : ((cls == 3) ? 1.0f : 0.0f);
        selA[q] = (cls == 0) ? 0 : ((cls == 2) ? 1 : 2);
    }
    for (int t = 0; t < 84; t++) {
        float4 zv = zb[w][t];
#pragma unroll
        for (int q = 0; q < 3; q++) {
            float zr = (selA[q] == 0) ? zv.x : ((selA[q] == 1) ? zv.y : zv.z);
            float zi = sgn[q] * zv.w;
            re[q] = fmaf(zr, cc[q], re[q]);
            re[q] = fmaf(zi, sn[q], re[q]);
            im[q] = fmaf(zi, cc[q], im[q]);
            im[q] = fmaf(-zr, sn[q], im[q]);
            float nc = fmaf(cc[q], cd[q], -(sn[q] * sd[q]));
            float ns = fmaf(sn[q], cd[q], cc[q] * sd[q]);
            cc[q] = nc; sn[q] = ns;
        }
    }

    ULL k0 = 0, k1 = 0, k2 = 0;
#pragma unroll
    for (int q = 0; q < 3; q++) {
        float a2 = fmaf(re[q], re[q], im[q] * im[q]);
        ULL key = ((ULL)__float_as_uint(a2) << 32) |
                  (ULL)(0xFFFFFFFFu - (unsigned)fb[q]);
        if (fb[q] > 168) key = 0ull;
        ins3(k0, k1, k2, key);
    }
    for (int m = 1; m < 64; m <<= 1) {
        ULL b0 = __shfl_xor(k0, m, 64);
        ULL b1 = __shfl_xor(k1, m, 64);
        ULL b2 = __shfl_xor(k2, m, 64);
        ins3(k0, k1, k2, b0); ins3(k0, k1, k2, b1); ins3(k0, k1, k2, b2);
    }

    int fr0 = (int)(0xFFFFFFFFu - (unsigned)(k0 & 0xFFFFFFFFull));
    int fr1 = (int)(0xFFFFFFFFu - (unsigned)(k1 & 0xFFFFFFFFull));
    int fr2 = (int)(0xFFFFFFFFu - (unsigned)(k2 & 0xFFFFFFFFull));

    double lsum = 0.0, lcnt = 0.0;
    patch_body(&ts[w][0], lane, fr0, fr1, fr2, lsum, lcnt);

    for (int off = 32; off; off >>= 1) {
        lsum += __shfl_down(lsum, off, 64);
        lcnt += __shfl_down(lcnt, off, 64);
    }
    if (lane == 0) {
        if (pairs) {
            pairs[ser] = make_double2(lsum, lcnt);
        } else {
            atomicAdd(&acc[1], lsum);
            atomicAdd(&acc[2], lcnt);
        }
    }
}

// ---------------------------------------------------------------------------
// Final reduction over per-block triples (ls, lc, ms): ~31 KB read.
// ---------------------------------------------------------------------------
__global__ __launch_bounds__(1024) void reduce3_k(const double* __restrict__ blkout,
                                                  float* __restrict__ out) {
    const int tid = threadIdx.x;
    double ls = 0.0, lc = 0.0, ms = 0.0;
    for (int i = tid; i < NFB; i += 1024) {
        ls += blkout[3 * i + 0];
        lc += blkout[3 * i + 1];
        ms += blkout[3 * i + 2];
    }
    for (int off = 32; off; off >>= 1) {
        ls += __shfl_down(ls, off, 64);
        lc += __shfl_down(lc, off, 64);
        ms += __shfl_down(ms, off, 64);
    }
    __shared__ double sl[16], sc[16], sm[16];
    int lane = tid & 63, wid = tid >> 6;
    if (lane == 0) { sl[wid] = ls; sc[wid] = lc; sm[wid] = ms; }
    __syncthreads();
    if (tid == 0) {
        double L = 0, C = 0, M = 0;
        for (int i = 0; i < 16; i++) { L += sl[i]; C += sc[i]; M += sm[i]; }
        double mse = M / (double)((size_t)NB * TT * NF);
        double avg = (C > 0.0) ? (L / C) : 0.0;
        out[0] = (float)(0.5 * mse + 0.5 * avg);
    }
}

// fallback reduce over pairs+msep (round-3 style)
__global__ __launch_bounds__(1024) void reduce_k(const double2* __restrict__ pairs,
                                                 const double* __restrict__ msep,
                                                 int nmse,
                                                 float* __restrict__ out) {
    const int tid = threadIdx.x;
    double ls = 0.0, lc = 0.0, ms = 0.0;
    for (int i = tid; i < NSER; i += 1024) {
        double2 p = pairs[i];
        ls += p.x; lc += p.y;
    }
    for (int i = tid; i < nmse; i += 1024) ms += msep[i];
    for (int off = 32; off; off >>= 1) {
        ls += __shfl_down(ls, off, 64);
        lc += __shfl_down(lc, off, 64);
        ms += __shfl_down(ms, off, 64);
    }
    __shared__ double sl[16], sc[16], sm[16];
    int lane = tid & 63, wid = tid >> 6;
    if (lane == 0) { sl[wid] = ls; sc[wid] = lc; sm[wid] = ms; }
    __syncthreads();
    if (tid == 0) {
        double L = 0, C = 0, M = 0;
        for (int i = 0; i < 16; i++) { L += sl[i]; C += sc[i]; M += sm[i]; }
        double mse = M / (double)((size_t)NB * TT * NF);
        double avg = (C > 0.0) ? (L / C) : 0.0;
        out[0] = (float)(0.5 * mse + 0.5 * avg);
    }
}

__global__ void finalize_k(const double* __restrict__ acc, float* __restrict__ out) {
    double mse = acc[0] / (double)((size_t)NB * TT * NF);
    double avg = (acc[2] > 0.0) ? (acc[1] / acc[2]) : 0.0;
    out[0] = (float)(0.5 * mse + 0.5 * avg);
}

// ---------------------------------------------------------------------------
extern "C" void kernel_launch(void* const* d_in, const int* in_sizes, int n_in,
                              void* d_out, int out_size, void* d_ws, size_t ws_size,
                              hipStream_t stream) {
    const float* fc = (const float*)d_in[0];   // forecast
    const float* tg = (const float*)d_in[1];   // target
    float* out = (float*)d_out;
    char* ws = (char*)d_ws;
    double* acc = (double*)ws;

    // layout: [0,64) acc | msep | blkout/pairs | (unused topk) | Wb | (fb tsT)
    const size_t OFF_MSE = 64;
    const size_t OFF_PAIR = OFF_MSE + (size_t)NMSEP * sizeof(double);        // 62016
    const size_t OFF_TOP = OFF_PAIR + (size_t)NSER * sizeof(double2);        // 390720
    const size_t OFF_W = OFF_TOP + (size_t)NSER * sizeof(uint4);             // 719424
    const size_t OFF_END2 = OFF_W + (size_t)TT * KP * sizeof(unsigned short);// 955968
    const size_t bytesT = (size_t)NSER * TT * sizeof(float2);
    const bool big2 = (ws_size >= OFF_END2);                   // main path
    const size_t R3_OFF_TS = OFF_PAIR + (size_t)NSER * sizeof(double2);
    const bool big = !big2 && (ws_size >= R3_OFF_TS + bytesT);
    const bool mid = !big2 && !big && (ws_size >= OFF_MSE + bytesT);

    double* msep = (double*)(ws + OFF_MSE);
    double* blkout = (double*)(ws + OFF_PAIR);   // 3*NFB doubles (31 KB)
    unsigned short* Wb = (unsigned short*)(ws + OFF_W);

    dim3 tg_grid(TGX, TGY, NB);
    dim3 tg_blk(32, 8);

    if (big2) {
        twiddle_k<<<TT, 128, 0, stream>>>(Wb);
        fused_k<<<NFBG, 64 * WV, 0, stream>>>(tg, fc, Wb, blkout);
        reduce3_k<<<1, 1024, 0, stream>>>(blkout, out);
    } else if (big) {
        float2* tsT = (float2*)(ws + R3_OFF_TS);
        transpose_k<<<tg_grid, tg_blk, 0, stream>>>(fc, tg, tsT, msep, acc);
        series_k<<<NSER / WPB, 64 * WPB, 0, stream>>>(tsT, fc, tg, 1,
                                                      (double2*)blkout, acc);
        reduce_k<<<1, 1024, 0, stream>>>((double2*)blkout, msep, NMSEP, out);
    } else if (mid) {
        float2* tsT = (float2*)(ws + OFF_MSE);
        hipMemsetAsync(d_ws, 0, 64, stream);
        transpose_k<<<tg_grid, tg_blk, 0, stream>>>(fc, tg, tsT, nullptr, acc);
        series_k<<<NSER / WPB, 64 * WPB, 0, stream>>>(tsT, fc, tg, 1, nullptr, acc);
        finalize_k<<<1, 1, 0, stream>>>(acc, out);
    } else {
        hipMemsetAsync(d_ws, 0, 64, stream);
        mse_k<<<1024, 256, 0, stream>>>(fc, tg, acc);
        series_k<<<NSER / WPB, 64 * WPB, 0, stream>>>(nullptr, fc, tg, 0, nullptr, acc);
        finalize_k<<<1, 1, 0, stream>>>(acc, out);
    }
}